// Round 2
// baseline (2011.435 us; speedup 1.0000x reference)
//
#include <hip/hip_runtime.h>
#include <hip/hip_bf16.h>
#include <math.h>

#define NB 32
#define NN 1000
#define SS 200
#define DD 128
#define HH 8
#define DKK 16
#define FFD 512
#define NLAYER 3
#define LQ 802
#define LPAD 832           // 26 k-tiles of 32 for PV
#define MROWS (NB*LQ)      // 25664
#define RTILE 16
#define NBLK (MROWS/RTILE) // 1604 exactly
#define SSTR 816           // S LDS stride (51*16)
#define PSTR 840           // P LDS stride (bf16), padded for bank spread

typedef __attribute__((ext_vector_type(8))) short short8;
typedef __attribute__((ext_vector_type(4))) float f32x4;

static __device__ __forceinline__ unsigned short f2bf(float x) {
  union { float f; unsigned int u; } v; v.f = x;
  unsigned int r = v.u + 0x7fff + ((v.u >> 16) & 1);   // RNE
  return (unsigned short)(r >> 16);
}

// ---------------- unselect + pos (inverse map) ----------------
__global__ __launch_bounds__(1024) void k_unselect(const int* __restrict__ sel,
                                                   int* __restrict__ unselect,
                                                   int* __restrict__ pos) {
  int b = blockIdx.x;
  int n = threadIdx.x;
  __shared__ int bufA[1024];
  __shared__ int bufB[1024];
  bufA[n] = (n < NN) ? 1 : 0;
  __syncthreads();
  if (n < SS) bufA[sel[b*SS + n]] = 0;
  __syncthreads();
  int flag = bufA[n];
  int* src = bufA; int* dst = bufB;
  for (int off = 1; off < 1024; off <<= 1) {
    int v = src[n];
    if (n >= off) v += src[n - off];
    __syncthreads();
    dst[n] = v;
    __syncthreads();
    int* tp = src; src = dst; dst = tp;
  }
  if (n < NN) {
    if (flag) {
      int j = src[n] - 1;
      unselect[b*800 + j] = n;
      pos[b*NN + n] = j + 1;
    } else {
      pos[b*NN + n] = -1;
    }
  }
}

// ---------------- build X = [ef, left, el] ----------------
__global__ __launch_bounds__(128) void k_embed(const float* __restrict__ data,
                       const int* __restrict__ sel, const int* __restrict__ unselect,
                       const float* __restrict__ Wfirst, const float* __restrict__ bfirst,
                       const float* __restrict__ Wlast, const float* __restrict__ blast,
                       float* __restrict__ X) {
  int l = blockIdx.x, b = blockIdx.y, d = threadIdx.x;
  float* xout = X + ((size_t)(b*LQ + l))*DD;
  if (l == 0 || l == LQ-1) {
    __shared__ float xr[DD];
    int src = sel[b*SS + (l == 0 ? 0 : SS-1)];
    const float* W    = (l == 0) ? Wfirst : Wlast;
    const float* bias = (l == 0) ? bfirst : blast;
    xr[d] = data[((size_t)b*NN + src)*DD + d];
    __syncthreads();
    float acc = bias[d];
    #pragma unroll 4
    for (int k = 0; k < DD; ++k) acc += xr[k] * W[k*DD + d];
    xout[d] = acc;
  } else {
    int nidx = unselect[b*800 + (l-1)];
    xout[d] = data[((size_t)b*NN + nidx)*DD + d];
  }
}

// ---------------- fused QKV projection -> bf16 Q(scaled), K, V^T ----------------
__global__ __launch_bounds__(384) void k_qkv(const float* __restrict__ X,
                     const float* __restrict__ Wq, const float* __restrict__ Wk,
                     const float* __restrict__ Wv,
                     unsigned short* __restrict__ Q, unsigned short* __restrict__ K,
                     unsigned short* __restrict__ Vt) {
  __shared__ float xs[RTILE][DD];
  int row0 = blockIdx.x * RTILE;
  int t = threadIdx.x;
  for (int idx = t; idx < RTILE*DD; idx += 384)
    xs[idx>>7][idx&127] = X[(size_t)(row0 + (idx>>7))*DD + (idx&127)];
  __syncthreads();
  int mi = t >> 7, cc = t & 127;
  const float* W = (mi == 0) ? Wq : (mi == 1) ? Wk : Wv;
  float acc[RTILE];
  #pragma unroll
  for (int r = 0; r < RTILE; ++r) acc[r] = 0.f;
  #pragma unroll 4
  for (int k = 0; k < DD; ++k) {
    float w = W[k*DD + cc];
    #pragma unroll
    for (int r = 0; r < RTILE; ++r) acc[r] += xs[r][k] * w;
  }
  int h = cc >> 4, d = cc & 15;
  #pragma unroll
  for (int r = 0; r < RTILE; ++r) {
    int g = row0 + r;
    int b = g / LQ, l = g - b*LQ;
    size_t bh = (size_t)(b*HH + h);
    if (mi == 0)      Q[(bh*LQ + l)*DKK + d]  = f2bf(acc[r] * 0.25f);
    else if (mi == 1) K[(bh*LQ + l)*DKK + d]  = f2bf(acc[r]);
    else              Vt[(bh*DKK + d)*LPAD + l] = f2bf(acc[r]);
  }
}

// ---------------- MFMA attention: 16 queries/block, full-row softmax ----------------
__global__ __launch_bounds__(256) void k_attn2(const unsigned short* __restrict__ Q,
                       const unsigned short* __restrict__ K,
                       const unsigned short* __restrict__ Vt,
                       float* __restrict__ O) {
  __shared__ float S[RTILE * SSTR];          // 52.2 KB (reused for PV reduction)
  __shared__ unsigned short P[RTILE * PSTR]; // 26.25 KB
  int b = blockIdx.z, h = blockIdx.y, q0 = blockIdx.x * RTILE;
  int t = threadIdx.x;
  int wave = t >> 6, lane = t & 63;
  int m = lane & 15, quad = lane >> 4;
  size_t bh = (size_t)(b*HH + h);

  // ---- pass 1: S = (Q*0.25) @ K^T via MFMA (dk=16 zero-padded to K=32) ----
  short8 aQ = {0,0,0,0,0,0,0,0};
  if (quad < 2) {
    int q = q0 + m; if (q > LQ-1) q = LQ-1;
    aQ = *(const short8*)&Q[(bh*LQ + q)*DKK + quad*8];
  }
  #pragma unroll
  for (int i = 0; i < 13; ++i) {
    int kt = i*4 + wave;
    if (kt < 51) {
      short8 bK = {0,0,0,0,0,0,0,0};
      if (quad < 2) {
        int key = kt*16 + m; if (key > LQ-1) key = LQ-1;
        bK = *(const short8*)&K[(bh*LQ + key)*DKK + quad*8];
      }
      f32x4 c = {0.f,0.f,0.f,0.f};
      c = __builtin_amdgcn_mfma_f32_16x16x32_bf16(aQ, bK, c, 0, 0, 0);
      #pragma unroll
      for (int r = 0; r < 4; ++r)
        S[(quad*4 + r)*SSTR + kt*16 + m] = c[r];
    }
  }
  __syncthreads();

  // ---- pass 2: row softmax (16 threads per row) ----
  {
    int row = t >> 4, c0 = t & 15;
    float mx = -INFINITY;
    for (int j = c0; j < LQ; j += 16) mx = fmaxf(mx, S[row*SSTR + j]);
    #pragma unroll
    for (int msk = 8; msk > 0; msk >>= 1) mx = fmaxf(mx, __shfl_xor(mx, msk));
    float sum = 0.f;
    for (int j = c0; j < LQ; j += 16) {
      float e = __expf(S[row*SSTR + j] - mx);
      S[row*SSTR + j] = e;
      sum += e;
    }
    #pragma unroll
    for (int msk = 8; msk > 0; msk >>= 1) sum += __shfl_xor(sum, msk);
    float inv = 1.f / sum;
    for (int j = c0; j < LPAD; j += 16)
      P[row*PSTR + j] = (j < LQ) ? f2bf(S[row*SSTR + j] * inv) : (unsigned short)0;
  }
  __syncthreads();

  // ---- pass 3: O = P @ V via MFMA, 4-way wave split over keys ----
  f32x4 c = {0.f,0.f,0.f,0.f};
  #pragma unroll
  for (int i = 0; i < 7; ++i) {
    int kt = i*4 + wave;
    if (kt < 26) {
      short8 aP = *(const short8*)&P[m*PSTR + kt*32 + quad*8];
      short8 bV = *(const short8*)&Vt[(bh*DKK + m)*LPAD + kt*32 + quad*8];
      c = __builtin_amdgcn_mfma_f32_16x16x32_bf16(aP, bV, c, 0, 0, 0);
    }
  }
  __syncthreads();  // S reads (pass 2) done; reuse S as reduction scratch
  float* red = S;
  #pragma unroll
  for (int r = 0; r < 4; ++r)
    red[wave*256 + (quad*4 + r)*16 + m] = c[r];
  __syncthreads();
  {
    int row = t >> 4, col = t & 15;
    float o = red[0*256 + row*16 + col] + red[1*256 + row*16 + col]
            + red[2*256 + row*16 + col] + red[3*256 + row*16 + col];
    int q = q0 + row;
    if (q < LQ)
      O[((size_t)(b*LQ + q))*DD + h*DKK + col] = o;
  }
}

// ---------------- attn output proj + residual (in-place X) ----------------
__global__ __launch_bounds__(128) void k_proj(const float* __restrict__ O,
                      const float* __restrict__ Wo, const float* __restrict__ bo,
                      float* __restrict__ X) {
  __shared__ float xs[RTILE][DD];
  int row0 = blockIdx.x * RTILE;
  int t = threadIdx.x;
  for (int idx = t; idx < RTILE*DD; idx += 128)
    xs[idx>>7][idx&127] = O[(size_t)(row0 + (idx>>7))*DD + (idx&127)];
  __syncthreads();
  float acc[RTILE];
  #pragma unroll
  for (int r = 0; r < RTILE; ++r) acc[r] = 0.f;
  #pragma unroll 4
  for (int k = 0; k < DD; ++k) {
    float w = Wo[k*DD + t];
    #pragma unroll
    for (int r = 0; r < RTILE; ++r) acc[r] += xs[r][k] * w;
  }
  float bv = bo[t];
  #pragma unroll
  for (int r = 0; r < RTILE; ++r) {
    size_t off = (size_t)(row0 + r)*DD + t;
    X[off] = X[off] + acc[r] + bv;
  }
}

// ---------------- fused FF: relu(X@W1+b1)@W2+b2 + residual (in-place X) ----------------
__global__ __launch_bounds__(512) void k_ff(const float* __restrict__ W1, const float* __restrict__ b1,
                    const float* __restrict__ W2, const float* __restrict__ b2,
                    float* __restrict__ X) {
  __shared__ float xs[RTILE][DD];
  __shared__ float hs[RTILE][FFD];
  int row0 = blockIdx.x * RTILE;
  int t = threadIdx.x;
  for (int idx = t; idx < RTILE*DD; idx += 512)
    xs[idx>>7][idx&127] = X[(size_t)(row0 + (idx>>7))*DD + (idx&127)];
  __syncthreads();
  {
    float acc[RTILE];
    #pragma unroll
    for (int r = 0; r < RTILE; ++r) acc[r] = 0.f;
    #pragma unroll 4
    for (int k = 0; k < DD; ++k) {
      float w = W1[k*FFD + t];
      #pragma unroll
      for (int r = 0; r < RTILE; ++r) acc[r] += xs[r][k] * w;
    }
    float bv = b1[t];
    #pragma unroll
    for (int r = 0; r < RTILE; ++r) hs[r][t] = fmaxf(acc[r] + bv, 0.f);
  }
  __syncthreads();
  int cc = t & 127, kg = t >> 7;
  float acc2[RTILE];
  #pragma unroll
  for (int r = 0; r < RTILE; ++r) acc2[r] = 0.f;
  #pragma unroll 4
  for (int k2 = 0; k2 < 128; ++k2) {
    int k = kg*128 + k2;
    float w = W2[k*DD + cc];
    #pragma unroll
    for (int r = 0; r < RTILE; ++r) acc2[r] += hs[r][k] * w;
  }
  __syncthreads();
  float* hf = &hs[0][0];
  #pragma unroll
  for (int r = 0; r < RTILE; ++r) hf[(kg*RTILE + r)*DD + cc] = acc2[r];
  __syncthreads();
  for (int idx = t; idx < RTILE*DD; idx += 512) {
    int r = idx >> 7, c = idx & 127;
    float sum = hf[(0*RTILE + r)*DD + c] + hf[(1*RTILE + r)*DD + c]
              + hf[(2*RTILE + r)*DD + c] + hf[(3*RTILE + r)*DD + c];
    size_t off = (size_t)(row0 + r)*DD + c;
    X[off] = xs[r][c] + sum + b2[c];
  }
}

// ---------------- logits = X @ Wfin + bfin ----------------
__global__ __launch_bounds__(128) void k_logits(const float* __restrict__ X,
                        const float* __restrict__ Wfin, const float* __restrict__ bfin,
                        float* __restrict__ logits) {
  int row = blockIdx.x, t = threadIdx.x;
  float v = X[(size_t)row*DD + t] * Wfin[t];
  #pragma unroll
  for (int off = 32; off > 0; off >>= 1) v += __shfl_down(v, off);
  __shared__ float s2[2];
  if ((t & 63) == 0) s2[t >> 6] = v;
  __syncthreads();
  if (t == 0) logits[row] = s2[0] + s2[1] + bfin[0];
}

// ---------------- bias add, softmax, epsilon, scatter ----------------
__global__ __launch_bounds__(256) void k_final(const float* __restrict__ logits,
                       const float* __restrict__ AB, const int* __restrict__ sel,
                       const int* __restrict__ unselect, const int* __restrict__ pos,
                       float* __restrict__ out) {
  int b = blockIdx.x, t = threadIdx.x;
  __shared__ float sl[800];
  __shared__ float red[256];
  int lastsel = sel[b*SS + SS-1];
  const float* abrow = AB + ((size_t)b*NN + lastsel)*NN;
  for (int j = t; j < 800; j += 256)
    sl[j] = logits[b*LQ + j + 1] + abrow[unselect[b*800 + j]];
  __syncthreads();
  float lm = -INFINITY;
  for (int j = t; j < 800; j += 256) lm = fmaxf(lm, sl[j]);
  red[t] = lm;
  __syncthreads();
  for (int s = 128; s > 0; s >>= 1) {
    if (t < s) red[t] = fmaxf(red[t], red[t+s]);
    __syncthreads();
  }
  float m = red[0];
  __syncthreads();
  float ls = 0.f;
  for (int j = t; j < 800; j += 256) ls += __expf(sl[j] - m);
  red[t] = ls;
  __syncthreads();
  for (int s = 128; s > 0; s >>= 1) {
    if (t < s) red[t] += red[t+s];
    __syncthreads();
  }
  float inv = 1.f / red[0];
  for (int n = t; n < NN; n += 256) {
    int p1 = pos[b*NN + n];
    float v = -2.0f;
    if (p1 >= 0) {
      float p = __expf(sl[p1-1] - m) * inv;
      if (p <= 1e-5f) p += 1e-7f;
      v = p;
    }
    out[(size_t)b*NN + n] = v;
  }
}

extern "C" void kernel_launch(void* const* d_in, const int* in_sizes, int n_in,
                              void* d_out, int out_size, void* d_ws, size_t ws_size,
                              hipStream_t stream) {
  const float* data   = (const float*)d_in[0];
  const float* AB     = (const float*)d_in[1];
  const float* Wfirst = (const float*)d_in[2];
  const float* bfirst = (const float*)d_in[3];
  const float* Wlast  = (const float*)d_in[4];
  const float* blast  = (const float*)d_in[5];
  const float* Wq     = (const float*)d_in[6];
  const float* Wk     = (const float*)d_in[7];
  const float* Wv     = (const float*)d_in[8];
  const float* Wo     = (const float*)d_in[9];
  const float* bo     = (const float*)d_in[10];
  const float* W1     = (const float*)d_in[11];
  const float* b1     = (const float*)d_in[12];
  const float* W2     = (const float*)d_in[13];
  const float* b2     = (const float*)d_in[14];
  const float* Wfin   = (const float*)d_in[15];
  const float* bfin   = (const float*)d_in[16];
  const int*   sel    = (const int*)d_in[17];
  float* out = (float*)d_out;
  (void)in_sizes; (void)n_in; (void)out_size; (void)ws_size;

  char* ws = (char*)d_ws;
  const size_t NELT = (size_t)MROWS * DD;        // 3,284,992 floats
  int*   UNSEL = (int*)ws;                       // 25600 ints
  int*   POS   = (int*)(ws + 102400);            // 32000 ints (ends 230400)
  float* X     = (float*)(ws + 230400);
  float* Ob    = X + NELT;
  unsigned short* Qb = (unsigned short*)(Ob + NELT);            // 32*8*802*16
  unsigned short* Kb = Qb + (size_t)NB*HH*LQ*DKK;
  unsigned short* Vt = Kb + (size_t)NB*HH*LQ*DKK;               // 32*8*16*832
  float* LOG = (float*)(Vt + (size_t)NB*HH*DKK*LPAD);           // 25664 floats

  k_unselect<<<NB, 1024, 0, stream>>>(sel, UNSEL, POS);
  k_embed<<<dim3(LQ, NB), 128, 0, stream>>>(data, sel, UNSEL, Wfirst, bfirst, Wlast, blast, X);
  for (int i = 0; i < NLAYER; ++i) {
    k_qkv <<<NBLK, 384, 0, stream>>>(X, Wq + (size_t)i*DD*DD, Wk + (size_t)i*DD*DD,
                                     Wv + (size_t)i*DD*DD, Qb, Kb, Vt);
    k_attn2<<<dim3(51, HH, NB), 256, 0, stream>>>(Qb, Kb, Vt, Ob);
    k_proj<<<NBLK, 128, 0, stream>>>(Ob, Wo + (size_t)i*DD*DD, bo + (size_t)i*DD, X);
    k_ff  <<<NBLK, 512, 0, stream>>>(W1 + (size_t)i*DD*FFD, b1 + (size_t)i*FFD,
                                     W2 + (size_t)i*FFD*DD, b2 + (size_t)i*DD, X);
  }
  k_logits<<<MROWS, 128, 0, stream>>>(X, Wfin, bfin, LOG);
  k_final<<<NB, 256, 0, stream>>>(LOG, AB, sel, UNSEL, POS, out);
}

// Round 4
// 1114.216 us; speedup vs baseline: 1.8052x; 1.8052x over previous
//
#include <hip/hip_runtime.h>
#include <hip/hip_bf16.h>
#include <math.h>

#define NB 32
#define NN 1000
#define SS 200
#define DD 128
#define HH 8
#define DKK 16
#define FFD 512
#define NLAYER 3
#define LQ 802
#define LPAD 832           // key padding (26 tiles of 32)
#define MROWS (NB*LQ)      // 25664
#define RTILE 16
#define NBLK (MROWS/RTILE) // 1604 exactly
#define NQT 26             // ceil(802/32) query tiles

typedef __attribute__((ext_vector_type(8))) short short8;
typedef __attribute__((ext_vector_type(16))) float f32x16;

static __device__ __forceinline__ unsigned short f2bf(float x) {
  union { float f; unsigned int u; } v; v.f = x;
  unsigned int r = v.u + 0x7fff + ((v.u >> 16) & 1);   // RNE
  return (unsigned short)(r >> 16);
}

// ---------------- unselect + pos (inverse map) ----------------
__global__ __launch_bounds__(1024) void k_unselect(const int* __restrict__ sel,
                                                   int* __restrict__ unselect,
                                                   int* __restrict__ pos) {
  int b = blockIdx.x;
  int n = threadIdx.x;
  __shared__ int bufA[1024];
  __shared__ int bufB[1024];
  bufA[n] = (n < NN) ? 1 : 0;
  __syncthreads();
  if (n < SS) bufA[sel[b*SS + n]] = 0;
  __syncthreads();
  int flag = bufA[n];
  int* src = bufA; int* dst = bufB;
  for (int off = 1; off < 1024; off <<= 1) {
    int v = src[n];
    if (n >= off) v += src[n - off];
    __syncthreads();
    dst[n] = v;
    __syncthreads();
    int* tp = src; src = dst; dst = tp;
  }
  if (n < NN) {
    if (flag) {
      int j = src[n] - 1;
      unselect[b*800 + j] = n;
      pos[b*NN + n] = j + 1;
    } else {
      pos[b*NN + n] = -1;
    }
  }
}

// ---------------- build X = [ef, left, el] ----------------
__global__ __launch_bounds__(128) void k_embed(const float* __restrict__ data,
                       const int* __restrict__ sel, const int* __restrict__ unselect,
                       const float* __restrict__ Wfirst, const float* __restrict__ bfirst,
                       const float* __restrict__ Wlast, const float* __restrict__ blast,
                       float* __restrict__ X) {
  int l = blockIdx.x, b = blockIdx.y, d = threadIdx.x;
  float* xout = X + ((size_t)(b*LQ + l))*DD;
  if (l == 0 || l == LQ-1) {
    __shared__ float xr[DD];
    int src = sel[b*SS + (l == 0 ? 0 : SS-1)];
    const float* W    = (l == 0) ? Wfirst : Wlast;
    const float* bias = (l == 0) ? bfirst : blast;
    xr[d] = data[((size_t)b*NN + src)*DD + d];
    __syncthreads();
    float acc = bias[d];
    #pragma unroll 4
    for (int k = 0; k < DD; ++k) acc += xr[k] * W[k*DD + d];
    xout[d] = acc;
  } else {
    int nidx = unselect[b*800 + (l-1)];
    xout[d] = data[((size_t)b*NN + nidx)*DD + d];
  }
}

// ---------------- fused QKV projection -> bf16 Q(scaled), K, V^T ----------------
__global__ __launch_bounds__(384) void k_qkv(const float* __restrict__ X,
                     const float* __restrict__ Wq, const float* __restrict__ Wk,
                     const float* __restrict__ Wv,
                     unsigned short* __restrict__ Q, unsigned short* __restrict__ K,
                     unsigned short* __restrict__ Vt) {
  __shared__ float xs[RTILE][DD];
  int row0 = blockIdx.x * RTILE;
  int t = threadIdx.x;
  for (int idx = t; idx < RTILE*DD; idx += 384)
    xs[idx>>7][idx&127] = X[(size_t)(row0 + (idx>>7))*DD + (idx&127)];
  __syncthreads();
  int mi = t >> 7, cc = t & 127;
  const float* W = (mi == 0) ? Wq : (mi == 1) ? Wk : Wv;
  float acc[RTILE];
  #pragma unroll
  for (int r = 0; r < RTILE; ++r) acc[r] = 0.f;
  #pragma unroll 4
  for (int k = 0; k < DD; ++k) {
    float w = W[k*DD + cc];
    #pragma unroll
    for (int r = 0; r < RTILE; ++r) acc[r] += xs[r][k] * w;
  }
  int h = cc >> 4, d = cc & 15;
  #pragma unroll
  for (int r = 0; r < RTILE; ++r) {
    int g = row0 + r;
    int b = g / LQ, l = g - b*LQ;
    size_t bh = (size_t)(b*HH + h);
    if (mi == 0)      Q[(bh*LQ + l)*DKK + d]  = f2bf(acc[r] * 0.25f);
    else if (mi == 1) K[(bh*LQ + l)*DKK + d]  = f2bf(acc[r]);
    else              Vt[(bh*DKK + d)*LPAD + l] = f2bf(acc[r]);
  }
}

// ---------------- flash attention via S^T = K·Q^T (32x32x16 MFMA) ----------------
// Grid: 1D, NQT*HH*NB blocks of 256. XCD swizzle: bid&7 selects bh%8 group.
// KEY INVARIANT: runm/runs are kept IDENTICAL across the half-pair (lanes l, l^32)
// by sharing the tile max — exchanged P values then have a consistent scale.
__global__ __launch_bounds__(256) void k_attn3(const unsigned short* __restrict__ Q,
                       const unsigned short* __restrict__ K,
                       const unsigned short* __restrict__ Vt,
                       float* __restrict__ O) {
  int bid = blockIdx.x;
  int g = bid & 7, i = bid >> 3;
  int bhg = i / NQT, qt = i - bhg*NQT;
  int bh = bhg*8 + g;
  int b = bh >> 3, h = bh & 7;
  int q0 = qt*32;
  size_t bhLQ = (size_t)bh * LQ;
  int t = threadIdx.x;
  int wave = t >> 6, lane = t & 63;
  int col = lane & 31;                    // query within tile (C col)
  int half = lane >> 5;
  bool hb = (half != 0);

  __shared__ float mw[4][32];
  __shared__ float sw[4][32];
  __shared__ float sfin[32];
  __shared__ float ored[4][16][32];       // 8 KB
  __shared__ float osum[32][17];          // padded

  // B-frag: Q^T — lane: n=col (query), k = half*8 + j
  int q = q0 + col; if (q > LQ-1) q = LQ-1;
  short8 bQ = *(const short8*)&Q[(bhLQ + q)*DKK + half*8];

  f32x16 oacc = {0.f,0.f,0.f,0.f,0.f,0.f,0.f,0.f,0.f,0.f,0.f,0.f,0.f,0.f,0.f,0.f};
  float runm = -INFINITY, runs = 0.f;

  for (int kt = wave; kt < NQT; kt += 4) {
    int key0 = kt*32;
    // A-frag: K — lane: m=col (key), k = half*8 + j
    int keyA = key0 + col; if (keyA > LQ-1) keyA = LQ-1;
    short8 aK = *(const short8*)&K[(bhLQ + keyA)*DKK + half*8];
    f32x16 c = {0.f,0.f,0.f,0.f,0.f,0.f,0.f,0.f,0.f,0.f,0.f,0.f,0.f,0.f,0.f,0.f};
    c = __builtin_amdgcn_mfma_f32_32x32x16_bf16(aK, bQ, c, 0, 0, 0);
    // c[r] = S^T[key0 + (r&3)+8*(r>>2)+4*half][q0+col]
    bool full = (key0 + 31 < LQ);
    float tm;
    if (full) {
      tm = c[0];
      #pragma unroll
      for (int r = 1; r < 16; ++r) tm = fmaxf(tm, c[r]);
    } else {
      tm = -INFINITY;
      #pragma unroll
      for (int r = 0; r < 16; ++r) {
        int key = key0 + (r&3) + 8*(r>>2) + 4*half;
        if (key < LQ) tm = fmaxf(tm, c[r]);
      }
    }
    // share tile max across the half-pair so exchanged P has consistent scale
    tm = fmaxf(tm, __shfl_xor(tm, 32, 64));
    float mnew = fmaxf(runm, tm);
    float scale = __expf(runm - mnew);    // first iter: exp(-inf)=0, oacc/runs already 0
    runs *= scale;
    #pragma unroll
    for (int r = 0; r < 8; ++r) oacc[r] *= scale;
    runm = mnew;
    float p[16];
    if (full) {
      #pragma unroll
      for (int r = 0; r < 16; ++r) p[r] = __expf(c[r] - mnew);
    } else {
      #pragma unroll
      for (int r = 0; r < 16; ++r) {
        int key = key0 + (r&3) + 8*(r>>2) + 4*half;
        p[r] = (key < LQ) ? __expf(c[r] - mnew) : 0.f;
      }
    }
    float ts = 0.f;
    #pragma unroll
    for (int r = 0; r < 16; ++r) ts += p[r];
    runs += ts;
    // pack pairs (truncate to bf16): pk[j] = (p[2j], p[2j+1])
    unsigned int pk[8];
    #pragma unroll
    for (int j = 0; j < 8; ++j) {
      unsigned int ua = __float_as_uint(p[2*j]);
      unsigned int ub = __float_as_uint(p[2*j+1]);
      pk[j] = (ua >> 16) | (ub & 0xffff0000u);
    }
    // half-exchange: each shuffle serves both halves
    int Y0 = __shfl_xor((int)(hb ? pk[0] : pk[2]), 32, 64);
    int Y1 = __shfl_xor((int)(hb ? pk[1] : pk[3]), 32, 64);
    int Y2 = __shfl_xor((int)(hb ? pk[4] : pk[6]), 32, 64);
    int Y3 = __shfl_xor((int)(hb ? pk[5] : pk[7]), 32, 64);
    union { int4 i4; short8 s8; } fA, fB;
    fA.i4.x = hb ? Y0 : (int)pk[0];
    fA.i4.y = hb ? Y1 : (int)pk[1];
    fA.i4.z = hb ? (int)pk[2] : Y0;
    fA.i4.w = hb ? (int)pk[3] : Y1;
    fB.i4.x = hb ? Y2 : (int)pk[4];
    fB.i4.y = hb ? Y3 : (int)pk[5];
    fB.i4.z = hb ? (int)pk[6] : Y2;
    fB.i4.w = hb ? (int)pk[7] : Y3;
    // V^T A-frags: lane m=col (dv, <16 valid), k = half*8 + j
    short8 aV0 = {0,0,0,0,0,0,0,0};
    short8 aV1 = {0,0,0,0,0,0,0,0};
    if (col < 16) {
      const unsigned short* vp = &Vt[((size_t)bh*DKK + col)*LPAD + key0 + half*8];
      aV0 = *(const short8*)vp;
      aV1 = *(const short8*)(vp + 16);
    }
    oacc = __builtin_amdgcn_mfma_f32_32x32x16_bf16(aV0, fA.s8, oacc, 0, 0, 0);
    oacc = __builtin_amdgcn_mfma_f32_32x32x16_bf16(aV1, fB.s8, oacc, 0, 0, 0);
  }

  // ---- merge halves (runm/runs identical across pair; general formula kept) ----
  float pm = __shfl_xor(runm, 32, 64);
  float ps = __shfl_xor(runs, 32, 64);
  float m2 = fmaxf(runm, pm);
  float fself = __expf(runm - m2);
  float s2 = runs*fself + ps*__expf(pm - m2);
  #pragma unroll
  for (int r = 0; r < 8; ++r) oacc[r] *= fself;
  if (half == 0) { mw[wave][col] = m2; sw[wave][col] = s2; }
  __syncthreads();
  // ---- merge waves ----
  float M = fmaxf(fmaxf(mw[0][col], mw[1][col]), fmaxf(mw[2][col], mw[3][col]));
  float S = sw[0][col]*__expf(mw[0][col]-M) + sw[1][col]*__expf(mw[1][col]-M)
          + sw[2][col]*__expf(mw[2][col]-M) + sw[3][col]*__expf(mw[3][col]-M);
  float fw = __expf(m2 - M);
  #pragma unroll
  for (int r = 0; r < 8; ++r) {
    int dv = (r&3) + 8*(r>>2) + 4*half;   // 0..15
    ored[wave][dv][col] = oacc[r] * fw;
  }
  if (wave == 0 && half == 0) sfin[col] = S;
  __syncthreads();
  // ---- reduce 4 waves -> osum[q][dv] ----
  {
    int qq = t & 31, dv0 = t >> 5;
    #pragma unroll
    for (int k = 0; k < 2; ++k) {
      int dv = dv0 + 8*k;
      osum[qq][dv] = ored[0][dv][qq] + ored[1][dv][qq] + ored[2][dv][qq] + ored[3][dv][qq];
    }
  }
  __syncthreads();
  // ---- normalize + store ----
  {
    int qs = t >> 3, c2 = (t & 7)*2;
    if (q0 + qs < LQ) {
      float invS = 1.f / sfin[qs];
      float2 val;
      val.x = osum[qs][c2]   * invS;
      val.y = osum[qs][c2+1] * invS;
      *(float2*)&O[((size_t)(b*LQ + q0 + qs))*DD + h*DKK + c2] = val;
    }
  }
}

// ---------------- attn output proj + residual (in-place X) ----------------
__global__ __launch_bounds__(128) void k_proj(const float* __restrict__ O,
                      const float* __restrict__ Wo, const float* __restrict__ bo,
                      float* __restrict__ X) {
  __shared__ float xs[RTILE][DD];
  int row0 = blockIdx.x * RTILE;
  int t = threadIdx.x;
  for (int idx = t; idx < RTILE*DD; idx += 128)
    xs[idx>>7][idx&127] = O[(size_t)(row0 + (idx>>7))*DD + (idx&127)];
  __syncthreads();
  float acc[RTILE];
  #pragma unroll
  for (int r = 0; r < RTILE; ++r) acc[r] = 0.f;
  #pragma unroll 4
  for (int k = 0; k < DD; ++k) {
    float w = Wo[k*DD + t];
    #pragma unroll
    for (int r = 0; r < RTILE; ++r) acc[r] += xs[r][k] * w;
  }
  float bv = bo[t];
  #pragma unroll
  for (int r = 0; r < RTILE; ++r) {
    size_t off = (size_t)(row0 + r)*DD + t;
    X[off] = X[off] + acc[r] + bv;
  }
}

// ---------------- fused FF: relu(X@W1+b1)@W2+b2 + residual (in-place X) ----------------
__global__ __launch_bounds__(512) void k_ff(const float* __restrict__ W1, const float* __restrict__ b1,
                    const float* __restrict__ W2, const float* __restrict__ b2,
                    float* __restrict__ X) {
  __shared__ float xs[RTILE][DD];
  __shared__ float hs[RTILE][FFD];
  int row0 = blockIdx.x * RTILE;
  int t = threadIdx.x;
  for (int idx = t; idx < RTILE*DD; idx += 512)
    xs[idx>>7][idx&127] = X[(size_t)(row0 + (idx>>7))*DD + (idx&127)];
  __syncthreads();
  {
    float acc[RTILE];
    #pragma unroll
    for (int r = 0; r < RTILE; ++r) acc[r] = 0.f;
    #pragma unroll 4
    for (int k = 0; k < DD; ++k) {
      float w = W1[k*FFD + t];
      #pragma unroll
      for (int r = 0; r < RTILE; ++r) acc[r] += xs[r][k] * w;
    }
    float bv = b1[t];
    #pragma unroll
    for (int r = 0; r < RTILE; ++r) hs[r][t] = fmaxf(acc[r] + bv, 0.f);
  }
  __syncthreads();
  int cc = t & 127, kg = t >> 7;
  float acc2[RTILE];
  #pragma unroll
  for (int r = 0; r < RTILE; ++r) acc2[r] = 0.f;
  #pragma unroll 4
  for (int k2 = 0; k2 < 128; ++k2) {
    int k = kg*128 + k2;
    float w = W2[k*DD + cc];
    #pragma unroll
    for (int r = 0; r < RTILE; ++r) acc2[r] += hs[r][k] * w;
  }
  __syncthreads();
  float* hf = &hs[0][0];
  #pragma unroll
  for (int r = 0; r < RTILE; ++r) hf[(kg*RTILE + r)*DD + cc] = acc2[r];
  __syncthreads();
  for (int idx = t; idx < RTILE*DD; idx += 512) {
    int r = idx >> 7, c = idx & 127;
    float sum = hf[(0*RTILE + r)*DD + c] + hf[(1*RTILE + r)*DD + c]
              + hf[(2*RTILE + r)*DD + c] + hf[(3*RTILE + r)*DD + c];
    size_t off = (size_t)(row0 + r)*DD + c;
    X[off] = xs[r][c] + sum + b2[c];
  }
}

// ---------------- logits = X @ Wfin + bfin ----------------
__global__ __launch_bounds__(128) void k_logits(const float* __restrict__ X,
                        const float* __restrict__ Wfin, const float* __restrict__ bfin,
                        float* __restrict__ logits) {
  int row = blockIdx.x, t = threadIdx.x;
  float v = X[(size_t)row*DD + t] * Wfin[t];
  #pragma unroll
  for (int off = 32; off > 0; off >>= 1) v += __shfl_down(v, off);
  __shared__ float s2[2];
  if ((t & 63) == 0) s2[t >> 6] = v;
  __syncthreads();
  if (t == 0) logits[row] = s2[0] + s2[1] + bfin[0];
}

// ---------------- bias add, softmax, epsilon, scatter ----------------
__global__ __launch_bounds__(256) void k_final(const float* __restrict__ logits,
                       const float* __restrict__ AB, const int* __restrict__ sel,
                       const int* __restrict__ unselect, const int* __restrict__ pos,
                       float* __restrict__ out) {
  int b = blockIdx.x, t = threadIdx.x;
  __shared__ float sl[800];
  __shared__ float red[256];
  int lastsel = sel[b*SS + SS-1];
  const float* abrow = AB + ((size_t)b*NN + lastsel)*NN;
  for (int j = t; j < 800; j += 256)
    sl[j] = logits[b*LQ + j + 1] + abrow[unselect[b*800 + j]];
  __syncthreads();
  float lm = -INFINITY;
  for (int j = t; j < 800; j += 256) lm = fmaxf(lm, sl[j]);
  red[t] = lm;
  __syncthreads();
  for (int s = 128; s > 0; s >>= 1) {
    if (t < s) red[t] = fmaxf(red[t], red[t+s]);
    __syncthreads();
  }
  float m = red[0];
  __syncthreads();
  float ls = 0.f;
  for (int j = t; j < 800; j += 256) ls += __expf(sl[j] - m);
  red[t] = ls;
  __syncthreads();
  for (int s = 128; s > 0; s >>= 1) {
    if (t < s) red[t] += red[t+s];
    __syncthreads();
  }
  float inv = 1.f / red[0];
  for (int n = t; n < NN; n += 256) {
    int p1 = pos[b*NN + n];
    float v = -2.0f;
    if (p1 >= 0) {
      float p = __expf(sl[p1-1] - m) * inv;
      if (p <= 1e-5f) p += 1e-7f;
      v = p;
    }
    out[(size_t)b*NN + n] = v;
  }
}

extern "C" void kernel_launch(void* const* d_in, const int* in_sizes, int n_in,
                              void* d_out, int out_size, void* d_ws, size_t ws_size,
                              hipStream_t stream) {
  const float* data   = (const float*)d_in[0];
  const float* AB     = (const float*)d_in[1];
  const float* Wfirst = (const float*)d_in[2];
  const float* bfirst = (const float*)d_in[3];
  const float* Wlast  = (const float*)d_in[4];
  const float* blast  = (const float*)d_in[5];
  const float* Wq     = (const float*)d_in[6];
  const float* Wk     = (const float*)d_in[7];
  const float* Wv     = (const float*)d_in[8];
  const float* Wo     = (const float*)d_in[9];
  const float* bo     = (const float*)d_in[10];
  const float* W1     = (const float*)d_in[11];
  const float* b1     = (const float*)d_in[12];
  const float* W2     = (const float*)d_in[13];
  const float* b2     = (const float*)d_in[14];
  const float* Wfin   = (const float*)d_in[15];
  const float* bfin   = (const float*)d_in[16];
  const int*   sel    = (const int*)d_in[17];
  float* out = (float*)d_out;
  (void)in_sizes; (void)n_in; (void)out_size; (void)ws_size;

  char* ws = (char*)d_ws;
  const size_t NELT = (size_t)MROWS * DD;
  int*   UNSEL = (int*)ws;
  int*   POS   = (int*)(ws + 102400);
  float* X     = (float*)(ws + 230400);
  float* Ob    = X + NELT;
  unsigned short* Qb = (unsigned short*)(Ob + NELT);
  unsigned short* Kb = Qb + (size_t)NB*HH*LQ*DKK;
  unsigned short* Vt = Kb + (size_t)NB*HH*LQ*DKK;
  float* LOG = (float*)(Vt + (size_t)NB*HH*DKK*LPAD);

  k_unselect<<<NB, 1024, 0, stream>>>(sel, UNSEL, POS);
  k_embed<<<dim3(LQ, NB), 128, 0, stream>>>(data, sel, UNSEL, Wfirst, bfirst, Wlast, blast, X);
  for (int i = 0; i < NLAYER; ++i) {
    k_qkv <<<NBLK, 384, 0, stream>>>(X, Wq + (size_t)i*DD*DD, Wk + (size_t)i*DD*DD,
                                     Wv + (size_t)i*DD*DD, Qb, Kb, Vt);
    k_attn3<<<NQT*HH*NB, 256, 0, stream>>>(Qb, Kb, Vt, Ob);
    k_proj<<<NBLK, 128, 0, stream>>>(Ob, Wo + (size_t)i*DD*DD, bo + (size_t)i*DD, X);
    k_ff  <<<NBLK, 512, 0, stream>>>(W1 + (size_t)i*DD*FFD, b1 + (size_t)i*FFD,
                                     W2 + (size_t)i*FFD*DD, b2 + (size_t)i*DD, X);
  }
  k_logits<<<MROWS, 128, 0, stream>>>(X, Wfin, bfin, LOG);
  k_final<<<NB, 256, 0, stream>>>(LOG, AB, sel, UNSEL, POS, out);
}

// Round 5
// 580.281 us; speedup vs baseline: 3.4663x; 1.9201x over previous
//
#include <hip/hip_runtime.h>
#include <hip/hip_bf16.h>
#include <math.h>

#define NB 32
#define NN 1000
#define SS 200
#define DD 128
#define HH 8
#define DKK 16
#define FFD 512
#define NLAYER 3
#define LQ 802
#define LPAD 832           // key padding (26 tiles of 32)
#define MROWS (NB*LQ)      // 25664
#define NBLK64 (MROWS/64)  // 401 exactly
#define NQT 26             // ceil(802/32) query tiles
#define HSTR 516           // H LDS stride (elements): 1032B -> 2-bank step, 2-way alias = free

typedef __attribute__((ext_vector_type(8))) short short8;
typedef __attribute__((ext_vector_type(4))) short short4v;
typedef __attribute__((ext_vector_type(16))) float f32x16;

static __device__ __forceinline__ unsigned short f2bf(float x) {
  union { float f; unsigned int u; } v; v.f = x;
  unsigned int r = v.u + 0x7fff + ((v.u >> 16) & 1);   // RNE
  return (unsigned short)(r >> 16);
}

// ---------------- weight transpose+convert: W[k][n] fp32 -> Wt[n][k] bf16 ----------------
// Layout per layer: WtQKV[384][128] (Q|K|V), Wot[128][128], W1t[512][128], W2t[128][512]
#define WCH 196608         // per-layer element count: 49152+16384+65536+65536
__global__ __launch_bounds__(256) void k_wconv(const float* __restrict__ Wq, const float* __restrict__ Wk,
                       const float* __restrict__ Wv, const float* __restrict__ Wo,
                       const float* __restrict__ W1, const float* __restrict__ W2,
                       unsigned short* __restrict__ WtQKV, unsigned short* __restrict__ Wot,
                       unsigned short* __restrict__ W1t, unsigned short* __restrict__ W2t) {
  int e = blockIdx.x*256 + threadIdx.x;
  if (e >= 3*WCH) return;
  int layer = e / WCH, r = e - layer*WCH;
  if (r < 49152) {
    int n = r >> 7, k = r & 127;
    int sect = n >> 7, nn = n & 127;
    const float* W = (sect == 0) ? Wq : (sect == 1) ? Wk : Wv;
    WtQKV[layer*49152 + r] = f2bf(W[layer*16384 + k*128 + nn]);
  } else if (r < 65536) {
    int r2 = r - 49152;
    int n = r2 >> 7, k = r2 & 127;
    Wot[layer*16384 + r2] = f2bf(Wo[layer*16384 + k*128 + n]);
  } else if (r < 131072) {
    int r2 = r - 65536;
    int n = r2 >> 7, k = r2 & 127;
    W1t[layer*65536 + r2] = f2bf(W1[layer*65536 + k*512 + n]);
  } else {
    int r2 = r - 131072;
    int n = r2 >> 9, k = r2 & 511;
    W2t[layer*65536 + r2] = f2bf(W2[layer*65536 + k*128 + n]);
  }
}

// ---------------- unselect + pos (inverse map) ----------------
__global__ __launch_bounds__(1024) void k_unselect(const int* __restrict__ sel,
                                                   int* __restrict__ unselect,
                                                   int* __restrict__ pos) {
  int b = blockIdx.x;
  int n = threadIdx.x;
  __shared__ int bufA[1024];
  __shared__ int bufB[1024];
  bufA[n] = (n < NN) ? 1 : 0;
  __syncthreads();
  if (n < SS) bufA[sel[b*SS + n]] = 0;
  __syncthreads();
  int flag = bufA[n];
  int* src = bufA; int* dst = bufB;
  for (int off = 1; off < 1024; off <<= 1) {
    int v = src[n];
    if (n >= off) v += src[n - off];
    __syncthreads();
    dst[n] = v;
    __syncthreads();
    int* tp = src; src = dst; dst = tp;
  }
  if (n < NN) {
    if (flag) {
      int j = src[n] - 1;
      unselect[b*800 + j] = n;
      pos[b*NN + n] = j + 1;
    } else {
      pos[b*NN + n] = -1;
    }
  }
}

// ---------------- build X = [ef, left, el] (fp32 + bf16 copy) ----------------
__global__ __launch_bounds__(128) void k_embed(const float* __restrict__ data,
                       const int* __restrict__ sel, const int* __restrict__ unselect,
                       const float* __restrict__ Wfirst, const float* __restrict__ bfirst,
                       const float* __restrict__ Wlast, const float* __restrict__ blast,
                       float* __restrict__ X, unsigned short* __restrict__ Xbf) {
  int l = blockIdx.x, b = blockIdx.y, d = threadIdx.x;
  size_t off = ((size_t)(b*LQ + l))*DD + d;
  float val;
  if (l == 0 || l == LQ-1) {
    __shared__ float xr[DD];
    int src = sel[b*SS + (l == 0 ? 0 : SS-1)];
    const float* W    = (l == 0) ? Wfirst : Wlast;
    const float* bias = (l == 0) ? bfirst : blast;
    xr[d] = data[((size_t)b*NN + src)*DD + d];
    __syncthreads();
    float acc = bias[d];
    #pragma unroll 4
    for (int k = 0; k < DD; ++k) acc += xr[k] * W[k*DD + d];
    val = acc;
  } else {
    int nidx = unselect[b*800 + (l-1)];
    val = data[((size_t)b*NN + nidx)*DD + d];
  }
  X[off] = val;
  Xbf[off] = f2bf(val);
}

// ---------------- MFMA QKV: C[M x 384] = Xbf @ [Wq|Wk|Wv], scatter to Q/K/Vt ----------------
__global__ __launch_bounds__(256) void k_qkv_mfma(const unsigned short* __restrict__ Xbf,
                       const unsigned short* __restrict__ Wt,   // [384][128]
                       unsigned short* __restrict__ Qb, unsigned short* __restrict__ Kb,
                       unsigned short* __restrict__ Vt) {
  int row0 = blockIdx.x * 64;
  int t = threadIdx.x, wave = t >> 6, lane = t & 63;
  int col = lane & 31, half = lane >> 5;
  // preload A-frags for both 32-row subtiles
  short8 a[2][8];
  const unsigned short* xb = Xbf + (size_t)(row0 + col)*DD + half*8;
  #pragma unroll
  for (int mi = 0; mi < 2; ++mi)
    #pragma unroll
    for (int s = 0; s < 8; ++s)
      a[mi][s] = *(const short8*)(xb + (size_t)mi*32*DD + s*16);
  #pragma unroll
  for (int nn = 0; nn < 3; ++nn) {
    int ni = wave*3 + nn;
    short8 bfr[8];
    const unsigned short* wb = Wt + (size_t)(ni*32 + col)*DD + half*8;
    #pragma unroll
    for (int s = 0; s < 8; ++s) bfr[s] = *(const short8*)(wb + s*16);
    f32x16 acc0 = {0.f,0.f,0.f,0.f,0.f,0.f,0.f,0.f,0.f,0.f,0.f,0.f,0.f,0.f,0.f,0.f};
    f32x16 acc1 = {0.f,0.f,0.f,0.f,0.f,0.f,0.f,0.f,0.f,0.f,0.f,0.f,0.f,0.f,0.f,0.f};
    #pragma unroll
    for (int s = 0; s < 8; ++s) {
      acc0 = __builtin_amdgcn_mfma_f32_32x32x16_bf16(a[0][s], bfr[s], acc0, 0, 0, 0);
      acc1 = __builtin_amdgcn_mfma_f32_32x32x16_bf16(a[1][s], bfr[s], acc1, 0, 0, 0);
    }
    int n = ni*32 + col;
    int sect = n >> 7, nc = n & 127;
    int h = nc >> 4, d = nc & 15;
    #pragma unroll
    for (int mi = 0; mi < 2; ++mi) {
      const f32x16& acc = mi ? acc1 : acc0;
      #pragma unroll
      for (int r = 0; r < 16; ++r) {
        int m = row0 + mi*32 + (r&3) + 8*(r>>2) + 4*half;
        int b_ = m / LQ, l = m - b_*LQ;
        size_t bh = (size_t)(b_*HH + h);
        float v = acc[r];
        if (sect == 0)      Qb[(bh*LQ + l)*DKK + d] = f2bf(v * 0.25f);
        else if (sect == 1) Kb[(bh*LQ + l)*DKK + d] = f2bf(v);
        else                Vt[(bh*DKK + d)*LPAD + l] = f2bf(v);
      }
    }
  }
}

// ---------------- flash attention via S^T = K·Q^T (32x32x16 MFMA) -> Obf bf16 ----------------
__global__ __launch_bounds__(256) void k_attn3(const unsigned short* __restrict__ Q,
                       const unsigned short* __restrict__ K,
                       const unsigned short* __restrict__ Vt,
                       unsigned short* __restrict__ Obf) {
  int bid = blockIdx.x;
  int g = bid & 7, i = bid >> 3;
  int bhg = i / NQT, qt = i - bhg*NQT;
  int bh = bhg*8 + g;
  int b = bh >> 3, h = bh & 7;
  int q0 = qt*32;
  size_t bhLQ = (size_t)bh * LQ;
  int t = threadIdx.x;
  int wave = t >> 6, lane = t & 63;
  int col = lane & 31;
  int half = lane >> 5;
  bool hb = (half != 0);

  __shared__ float mw[4][32];
  __shared__ float sw[4][32];
  __shared__ float sfin[32];
  __shared__ float ored[4][16][32];
  __shared__ float osum[32][17];

  int q = q0 + col; if (q > LQ-1) q = LQ-1;
  short8 bQ = *(const short8*)&Q[(bhLQ + q)*DKK + half*8];

  f32x16 oacc = {0.f,0.f,0.f,0.f,0.f,0.f,0.f,0.f,0.f,0.f,0.f,0.f,0.f,0.f,0.f,0.f};
  float runm = -INFINITY, runs = 0.f;

  for (int kt = wave; kt < NQT; kt += 4) {
    int key0 = kt*32;
    int keyA = key0 + col; if (keyA > LQ-1) keyA = LQ-1;
    short8 aK = *(const short8*)&K[(bhLQ + keyA)*DKK + half*8];
    f32x16 c = {0.f,0.f,0.f,0.f,0.f,0.f,0.f,0.f,0.f,0.f,0.f,0.f,0.f,0.f,0.f,0.f};
    c = __builtin_amdgcn_mfma_f32_32x32x16_bf16(aK, bQ, c, 0, 0, 0);
    bool full = (key0 + 31 < LQ);
    float tm;
    if (full) {
      tm = c[0];
      #pragma unroll
      for (int r = 1; r < 16; ++r) tm = fmaxf(tm, c[r]);
    } else {
      tm = -INFINITY;
      #pragma unroll
      for (int r = 0; r < 16; ++r) {
        int key = key0 + (r&3) + 8*(r>>2) + 4*half;
        if (key < LQ) tm = fmaxf(tm, c[r]);
      }
    }
    tm = fmaxf(tm, __shfl_xor(tm, 32, 64));   // keep half-pair consistent
    float mnew = fmaxf(runm, tm);
    float scale = __expf(runm - mnew);
    runs *= scale;
    #pragma unroll
    for (int r = 0; r < 8; ++r) oacc[r] *= scale;
    runm = mnew;
    float p[16];
    if (full) {
      #pragma unroll
      for (int r = 0; r < 16; ++r) p[r] = __expf(c[r] - mnew);
    } else {
      #pragma unroll
      for (int r = 0; r < 16; ++r) {
        int key = key0 + (r&3) + 8*(r>>2) + 4*half;
        p[r] = (key < LQ) ? __expf(c[r] - mnew) : 0.f;
      }
    }
    float ts = 0.f;
    #pragma unroll
    for (int r = 0; r < 16; ++r) ts += p[r];
    runs += ts;
    unsigned int pk[8];
    #pragma unroll
    for (int j = 0; j < 8; ++j) {
      unsigned int ua = __float_as_uint(p[2*j]);
      unsigned int ub = __float_as_uint(p[2*j+1]);
      pk[j] = (ua >> 16) | (ub & 0xffff0000u);
    }
    int Y0 = __shfl_xor((int)(hb ? pk[0] : pk[2]), 32, 64);
    int Y1 = __shfl_xor((int)(hb ? pk[1] : pk[3]), 32, 64);
    int Y2 = __shfl_xor((int)(hb ? pk[4] : pk[6]), 32, 64);
    int Y3 = __shfl_xor((int)(hb ? pk[5] : pk[7]), 32, 64);
    union { int4 i4; short8 s8; } fA, fB;
    fA.i4.x = hb ? Y0 : (int)pk[0];
    fA.i4.y = hb ? Y1 : (int)pk[1];
    fA.i4.z = hb ? (int)pk[2] : Y0;
    fA.i4.w = hb ? (int)pk[3] : Y1;
    fB.i4.x = hb ? Y2 : (int)pk[4];
    fB.i4.y = hb ? Y3 : (int)pk[5];
    fB.i4.z = hb ? (int)pk[6] : Y2;
    fB.i4.w = hb ? (int)pk[7] : Y3;
    short8 aV0 = {0,0,0,0,0,0,0,0};
    short8 aV1 = {0,0,0,0,0,0,0,0};
    if (col < 16) {
      const unsigned short* vp = &Vt[((size_t)bh*DKK + col)*LPAD + key0 + half*8];
      aV0 = *(const short8*)vp;
      aV1 = *(const short8*)(vp + 16);
    }
    oacc = __builtin_amdgcn_mfma_f32_32x32x16_bf16(aV0, fA.s8, oacc, 0, 0, 0);
    oacc = __builtin_amdgcn_mfma_f32_32x32x16_bf16(aV1, fB.s8, oacc, 0, 0, 0);
  }

  float pm = __shfl_xor(runm, 32, 64);
  float ps = __shfl_xor(runs, 32, 64);
  float m2 = fmaxf(runm, pm);
  float fself = __expf(runm - m2);
  float s2 = runs*fself + ps*__expf(pm - m2);
  #pragma unroll
  for (int r = 0; r < 8; ++r) oacc[r] *= fself;
  if (half == 0) { mw[wave][col] = m2; sw[wave][col] = s2; }
  __syncthreads();
  float M = fmaxf(fmaxf(mw[0][col], mw[1][col]), fmaxf(mw[2][col], mw[3][col]));
  float S = sw[0][col]*__expf(mw[0][col]-M) + sw[1][col]*__expf(mw[1][col]-M)
          + sw[2][col]*__expf(mw[2][col]-M) + sw[3][col]*__expf(mw[3][col]-M);
  float fw = __expf(m2 - M);
  #pragma unroll
  for (int r = 0; r < 8; ++r) {
    int dv = (r&3) + 8*(r>>2) + 4*half;
    ored[wave][dv][col] = oacc[r] * fw;
  }
  if (wave == 0 && half == 0) sfin[col] = S;
  __syncthreads();
  {
    int qq = t & 31, dv0 = t >> 5;
    #pragma unroll
    for (int k = 0; k < 2; ++k) {
      int dv = dv0 + 8*k;
      osum[qq][dv] = ored[0][dv][qq] + ored[1][dv][qq] + ored[2][dv][qq] + ored[3][dv][qq];
    }
  }
  __syncthreads();
  {
    int qs = t >> 3, c2 = (t & 7)*2;
    if (q0 + qs < LQ) {
      float invS = 1.f / sfin[qs];
      unsigned int lo = f2bf(osum[qs][c2]   * invS);
      unsigned int hi = f2bf(osum[qs][c2+1] * invS);
      *(unsigned int*)&Obf[((size_t)(b*LQ + q0 + qs))*DD + h*DKK + c2] = lo | (hi << 16);
    }
  }
}

// ---------------- MFMA proj: X += Obf @ Wo + bo; refresh Xbf ----------------
__global__ __launch_bounds__(256) void k_proj_mfma(const unsigned short* __restrict__ Obf,
                       const unsigned short* __restrict__ Wot,  // [128][128]
                       const float* __restrict__ bo,
                       float* __restrict__ X, unsigned short* __restrict__ Xbf) {
  int row0 = blockIdx.x * 64;
  int t = threadIdx.x, wave = t >> 6, lane = t & 63;
  int col = lane & 31, half = lane >> 5;
  short8 a[2][8];
  const unsigned short* ob = Obf + (size_t)(row0 + col)*DD + half*8;
  #pragma unroll
  for (int mi = 0; mi < 2; ++mi)
    #pragma unroll
    for (int s = 0; s < 8; ++s)
      a[mi][s] = *(const short8*)(ob + (size_t)mi*32*DD + s*16);
  int ni = wave;
  short8 bfr[8];
  const unsigned short* wb = Wot + (size_t)(ni*32 + col)*DD + half*8;
  #pragma unroll
  for (int s = 0; s < 8; ++s) bfr[s] = *(const short8*)(wb + s*16);
  f32x16 acc0 = {0.f,0.f,0.f,0.f,0.f,0.f,0.f,0.f,0.f,0.f,0.f,0.f,0.f,0.f,0.f,0.f};
  f32x16 acc1 = {0.f,0.f,0.f,0.f,0.f,0.f,0.f,0.f,0.f,0.f,0.f,0.f,0.f,0.f,0.f,0.f};
  #pragma unroll
  for (int s = 0; s < 8; ++s) {
    acc0 = __builtin_amdgcn_mfma_f32_32x32x16_bf16(a[0][s], bfr[s], acc0, 0, 0, 0);
    acc1 = __builtin_amdgcn_mfma_f32_32x32x16_bf16(a[1][s], bfr[s], acc1, 0, 0, 0);
  }
  int n = ni*32 + col;
  float bv = bo[n];
  #pragma unroll
  for (int mi = 0; mi < 2; ++mi) {
    const f32x16& acc = mi ? acc1 : acc0;
    #pragma unroll
    for (int r = 0; r < 16; ++r) {
      int m = row0 + mi*32 + (r&3) + 8*(r>>2) + 4*half;
      size_t off = (size_t)m*DD + n;
      float res = X[off] + acc[r] + bv;
      X[off] = res;
      Xbf[off] = f2bf(res);
    }
  }
}

// ---------------- MFMA fused FF: X += relu(Xbf@W1+b1)@W2 + b2; refresh Xbf ----------------
__global__ __launch_bounds__(256) void k_ff_mfma(const unsigned short* __restrict__ Xbf_in,
                       const unsigned short* __restrict__ W1t,  // [512][128]
                       const float* __restrict__ b1,
                       const unsigned short* __restrict__ W2t,  // [128][512]
                       const float* __restrict__ b2,
                       float* __restrict__ X, unsigned short* __restrict__ Xbf) {
  __shared__ __align__(16) unsigned short Hs[64 * HSTR];  // ~64.5 KB
  int row0 = blockIdx.x * 64;
  int t = threadIdx.x, wave = t >> 6, lane = t & 63;
  int col = lane & 31, half = lane >> 5;
  // ---- phase 1: H = relu(Xbf @ W1 + b1) -> LDS bf16 ----
  short8 a[2][8];
  const unsigned short* xb = Xbf_in + (size_t)(row0 + col)*DD + half*8;
  #pragma unroll
  for (int mi = 0; mi < 2; ++mi)
    #pragma unroll
    for (int s = 0; s < 8; ++s)
      a[mi][s] = *(const short8*)(xb + (size_t)mi*32*DD + s*16);
  #pragma unroll
  for (int nn = 0; nn < 4; ++nn) {
    int ni = wave*4 + nn;
    short8 bfr[8];
    const unsigned short* wb = W1t + (size_t)(ni*32 + col)*DD + half*8;
    #pragma unroll
    for (int s = 0; s < 8; ++s) bfr[s] = *(const short8*)(wb + s*16);
    f32x16 acc0 = {0.f,0.f,0.f,0.f,0.f,0.f,0.f,0.f,0.f,0.f,0.f,0.f,0.f,0.f,0.f,0.f};
    f32x16 acc1 = {0.f,0.f,0.f,0.f,0.f,0.f,0.f,0.f,0.f,0.f,0.f,0.f,0.f,0.f,0.f,0.f};
    #pragma unroll
    for (int s = 0; s < 8; ++s) {
      acc0 = __builtin_amdgcn_mfma_f32_32x32x16_bf16(a[0][s], bfr[s], acc0, 0, 0, 0);
      acc1 = __builtin_amdgcn_mfma_f32_32x32x16_bf16(a[1][s], bfr[s], acc1, 0, 0, 0);
    }
    int n = ni*32 + col;
    float bv = b1[n];
    #pragma unroll
    for (int mi = 0; mi < 2; ++mi) {
      const f32x16& acc = mi ? acc1 : acc0;
      #pragma unroll
      for (int r = 0; r < 16; ++r) {
        int ml = mi*32 + (r&3) + 8*(r>>2) + 4*half;
        Hs[ml*HSTR + n] = f2bf(fmaxf(acc[r] + bv, 0.f));
      }
    }
  }
  __syncthreads();
  // ---- phase 2: C = H @ W2 (K=512), epilogue residual ----
  int ni = wave;
  f32x16 acc0 = {0.f,0.f,0.f,0.f,0.f,0.f,0.f,0.f,0.f,0.f,0.f,0.f,0.f,0.f,0.f,0.f};
  f32x16 acc1 = {0.f,0.f,0.f,0.f,0.f,0.f,0.f,0.f,0.f,0.f,0.f,0.f,0.f,0.f,0.f,0.f};
  const unsigned short* w2b = W2t + (size_t)(ni*32 + col)*FFD + half*8;
  #pragma unroll 4
  for (int s = 0; s < 32; ++s) {
    int ko = s*16 + half*8;
    union { short4v h[2]; short8 v; } h0, h1;
    const unsigned short* hp0 = &Hs[col*HSTR + ko];
    const unsigned short* hp1 = &Hs[(32 + col)*HSTR + ko];
    h0.h[0] = *(const short4v*)hp0;  h0.h[1] = *(const short4v*)(hp0 + 4);
    h1.h[0] = *(const short4v*)hp1;  h1.h[1] = *(const short4v*)(hp1 + 4);
    short8 bfr = *(const short8*)(w2b + s*16);
    acc0 = __builtin_amdgcn_mfma_f32_32x32x16_bf16(h0.v, bfr, acc0, 0, 0, 0);
    acc1 = __builtin_amdgcn_mfma_f32_32x32x16_bf16(h1.v, bfr, acc1, 0, 0, 0);
  }
  int n = ni*32 + col;
  float bv = b2[n];
  #pragma unroll
  for (int mi = 0; mi < 2; ++mi) {
    const f32x16& acc = mi ? acc1 : acc0;
    #pragma unroll
    for (int r = 0; r < 16; ++r) {
      int m = row0 + mi*32 + (r&3) + 8*(r>>2) + 4*half;
      size_t off = (size_t)m*DD + n;
      float res = X[off] + acc[r] + bv;
      X[off] = res;
      Xbf[off] = f2bf(res);
    }
  }
}

// ---------------- logits = X @ Wfin + bfin ----------------
__global__ __launch_bounds__(128) void k_logits(const float* __restrict__ X,
                        const float* __restrict__ Wfin, const float* __restrict__ bfin,
                        float* __restrict__ logits) {
  int row = blockIdx.x, t = threadIdx.x;
  float v = X[(size_t)row*DD + t] * Wfin[t];
  #pragma unroll
  for (int off = 32; off > 0; off >>= 1) v += __shfl_down(v, off);
  __shared__ float s2[2];
  if ((t & 63) == 0) s2[t >> 6] = v;
  __syncthreads();
  if (t == 0) logits[row] = s2[0] + s2[1] + bfin[0];
}

// ---------------- bias add, softmax, epsilon, scatter ----------------
__global__ __launch_bounds__(256) void k_final(const float* __restrict__ logits,
                       const float* __restrict__ AB, const int* __restrict__ sel,
                       const int* __restrict__ unselect, const int* __restrict__ pos,
                       float* __restrict__ out) {
  int b = blockIdx.x, t = threadIdx.x;
  __shared__ float sl[800];
  __shared__ float red[256];
  int lastsel = sel[b*SS + SS-1];
  const float* abrow = AB + ((size_t)b*NN + lastsel)*NN;
  for (int j = t; j < 800; j += 256)
    sl[j] = logits[b*LQ + j + 1] + abrow[unselect[b*800 + j]];
  __syncthreads();
  float lm = -INFINITY;
  for (int j = t; j < 800; j += 256) lm = fmaxf(lm, sl[j]);
  red[t] = lm;
  __syncthreads();
  for (int s = 128; s > 0; s >>= 1) {
    if (t < s) red[t] = fmaxf(red[t], red[t+s]);
    __syncthreads();
  }
  float m = red[0];
  __syncthreads();
  float ls = 0.f;
  for (int j = t; j < 800; j += 256) ls += __expf(sl[j] - m);
  red[t] = ls;
  __syncthreads();
  for (int s = 128; s > 0; s >>= 1) {
    if (t < s) red[t] += red[t+s];
    __syncthreads();
  }
  float inv = 1.f / red[0];
  for (int n = t; n < NN; n += 256) {
    int p1 = pos[b*NN + n];
    float v = -2.0f;
    if (p1 >= 0) {
      float p = __expf(sl[p1-1] - m) * inv;
      if (p <= 1e-5f) p += 1e-7f;
      v = p;
    }
    out[(size_t)b*NN + n] = v;
  }
}

extern "C" void kernel_launch(void* const* d_in, const int* in_sizes, int n_in,
                              void* d_out, int out_size, void* d_ws, size_t ws_size,
                              hipStream_t stream) {
  const float* data   = (const float*)d_in[0];
  const float* AB     = (const float*)d_in[1];
  const float* Wfirst = (const float*)d_in[2];
  const float* bfirst = (const float*)d_in[3];
  const float* Wlast  = (const float*)d_in[4];
  const float* blast  = (const float*)d_in[5];
  const float* Wq     = (const float*)d_in[6];
  const float* Wk     = (const float*)d_in[7];
  const float* Wv     = (const float*)d_in[8];
  const float* Wo     = (const float*)d_in[9];
  const float* bo     = (const float*)d_in[10];
  const float* W1     = (const float*)d_in[11];
  const float* b1     = (const float*)d_in[12];
  const float* W2     = (const float*)d_in[13];
  const float* b2     = (const float*)d_in[14];
  const float* Wfin   = (const float*)d_in[15];
  const float* bfin   = (const float*)d_in[16];
  const int*   sel    = (const int*)d_in[17];
  float* out = (float*)d_out;
  (void)in_sizes; (void)n_in; (void)out_size; (void)ws_size;

  char* ws = (char*)d_ws;
  const size_t NELT = (size_t)MROWS * DD;       // 3,284,992
  int*   UNSEL = (int*)ws;                      // 102,400 B
  int*   POS   = (int*)(ws + 102400);           // 128,000 B -> ends 230,400
  float* X     = (float*)(ws + 230400);         // 13.1 MB
  unsigned short* Xbf = (unsigned short*)(X + NELT);
  unsigned short* Ob  = Xbf + NELT;
  unsigned short* Qb  = Ob + NELT;              // 32*8*802*16
  unsigned short* Kb  = Qb + (size_t)NB*HH*LQ*DKK;
  unsigned short* Vt  = Kb + (size_t)NB*HH*LQ*DKK;  // 32*8*16*832
  unsigned short* WtQKV = Vt + (size_t)NB*HH*DKK*LPAD;
  unsigned short* Wot = WtQKV + (size_t)NLAYER*384*128;
  unsigned short* W1t = Wot + (size_t)NLAYER*128*128;
  unsigned short* W2t = W1t + (size_t)NLAYER*512*128;
  float* LOG = (float*)(W2t + (size_t)NLAYER*128*512);  // total ~48 MB

  k_wconv<<<(3*WCH + 255)/256, 256, 0, stream>>>(Wq, Wk, Wv, Wo, W1, W2, WtQKV, Wot, W1t, W2t);
  k_unselect<<<NB, 1024, 0, stream>>>(sel, UNSEL, POS);
  k_embed<<<dim3(LQ, NB), 128, 0, stream>>>(data, sel, UNSEL, Wfirst, bfirst, Wlast, blast, X, Xbf);
  for (int i = 0; i < NLAYER; ++i) {
    k_qkv_mfma<<<NBLK64, 256, 0, stream>>>(Xbf, WtQKV + (size_t)i*384*128, Qb, Kb, Vt);
    k_attn3<<<NQT*HH*NB, 256, 0, stream>>>(Qb, Kb, Vt, Ob);
    k_proj_mfma<<<NBLK64, 256, 0, stream>>>(Ob, Wot + (size_t)i*128*128, bo + (size_t)i*DD, X, Xbf);
    k_ff_mfma<<<NBLK64, 256, 0, stream>>>(Xbf, W1t + (size_t)i*512*128, b1 + (size_t)i*FFD,
                                          W2t + (size_t)i*128*512, b2 + (size_t)i*DD, X, Xbf);
  }
  k_logits<<<MROWS, 128, 0, stream>>>(X, Wfin, bfin, LOG);
  k_final<<<NB, 256, 0, stream>>>(LOG, AB, sel, UNSEL, POS, out);
}

// Round 6
// 572.749 us; speedup vs baseline: 3.5119x; 1.0131x over previous
//
#include <hip/hip_runtime.h>
#include <hip/hip_bf16.h>
#include <math.h>

#define NB 32
#define NN 1000
#define SS 200
#define DD 128
#define HH 8
#define DKK 16
#define FFD 512
#define NLAYER 3
#define LQ 802
#define MROWS (NB*LQ)      // 25664
#define NBLK64 (MROWS/64)  // 401 exactly
#define NQT 26             // key tiles of 32
#define NQT64 13           // query tiles of 64
#define HSTR 516           // H LDS stride (shorts): 2-bank step -> 2-way alias = free
#define TSTR 132           // T LDS stride (shorts): 2-bank step -> 2-way alias = free

typedef __attribute__((ext_vector_type(8))) short short8;
typedef __attribute__((ext_vector_type(4))) short short4v;
typedef __attribute__((ext_vector_type(16))) float f32x16;

static __device__ __forceinline__ unsigned short f2bf(float x) {
  union { float f; unsigned int u; } v; v.f = x;
  unsigned int r = v.u + 0x7fff + ((v.u >> 16) & 1);   // RNE
  return (unsigned short)(r >> 16);
}

// ---------------- weight transpose+convert: W[k][n] fp32 -> Wt[n][k] bf16 ----------------
#define WCH 196608         // per-layer: 49152+16384+65536+65536
__global__ __launch_bounds__(256) void k_wconv(const float* __restrict__ Wq, const float* __restrict__ Wk,
                       const float* __restrict__ Wv, const float* __restrict__ Wo,
                       const float* __restrict__ W1, const float* __restrict__ W2,
                       unsigned short* __restrict__ WtQKV, unsigned short* __restrict__ Wot,
                       unsigned short* __restrict__ W1t, unsigned short* __restrict__ W2t) {
  int e = blockIdx.x*256 + threadIdx.x;
  if (e >= 3*WCH) return;
  int layer = e / WCH, r = e - layer*WCH;
  if (r < 49152) {
    int n = r >> 7, k = r & 127;
    int sect = n >> 7, nn = n & 127;
    const float* W = (sect == 0) ? Wq : (sect == 1) ? Wk : Wv;
    WtQKV[layer*49152 + r] = f2bf(W[layer*16384 + k*128 + nn]);
  } else if (r < 65536) {
    int r2 = r - 49152;
    int n = r2 >> 7, k = r2 & 127;
    Wot[layer*16384 + r2] = f2bf(Wo[layer*16384 + k*128 + n]);
  } else if (r < 131072) {
    int r2 = r - 65536;
    int n = r2 >> 7, k = r2 & 127;
    W1t[layer*65536 + r2] = f2bf(W1[layer*65536 + k*512 + n]);
  } else {
    int r2 = r - 131072;
    int n = r2 >> 9, k = r2 & 511;
    W2t[layer*65536 + r2] = f2bf(W2[layer*65536 + k*128 + n]);
  }
}

// ---------------- unselect + pos (inverse map) ----------------
__global__ __launch_bounds__(1024) void k_unselect(const int* __restrict__ sel,
                                                   int* __restrict__ unselect,
                                                   int* __restrict__ pos) {
  int b = blockIdx.x;
  int n = threadIdx.x;
  __shared__ int bufA[1024];
  __shared__ int bufB[1024];
  bufA[n] = (n < NN) ? 1 : 0;
  __syncthreads();
  if (n < SS) bufA[sel[b*SS + n]] = 0;
  __syncthreads();
  int flag = bufA[n];
  int* src = bufA; int* dst = bufB;
  for (int off = 1; off < 1024; off <<= 1) {
    int v = src[n];
    if (n >= off) v += src[n - off];
    __syncthreads();
    dst[n] = v;
    __syncthreads();
    int* tp = src; src = dst; dst = tp;
  }
  if (n < NN) {
    if (flag) {
      int j = src[n] - 1;
      unselect[b*800 + j] = n;
      pos[b*NN + n] = j + 1;
    } else {
      pos[b*NN + n] = -1;
    }
  }
}

// ---------------- X ends: rows 0 and LQ-1 (matvec) ----------------
__global__ __launch_bounds__(128) void k_embed_ends(const float* __restrict__ data,
                       const int* __restrict__ sel,
                       const float* __restrict__ Wfirst, const float* __restrict__ bfirst,
                       const float* __restrict__ Wlast, const float* __restrict__ blast,
                       float* __restrict__ X, unsigned short* __restrict__ Xbf) {
  int which = blockIdx.x, b = blockIdx.y, d = threadIdx.x;
  int l = (which == 0) ? 0 : LQ-1;
  __shared__ float xr[DD];
  int src = sel[b*SS + (which == 0 ? 0 : SS-1)];
  const float* W    = (which == 0) ? Wfirst : Wlast;
  const float* bias = (which == 0) ? bfirst : blast;
  xr[d] = data[((size_t)b*NN + src)*DD + d];
  __syncthreads();
  float acc = bias[d];
  #pragma unroll 4
  for (int k = 0; k < DD; ++k) acc += xr[k] * W[k*DD + d];
  size_t off = ((size_t)(b*LQ + l))*DD + d;
  X[off] = acc;
  Xbf[off] = f2bf(acc);
}

// ---------------- X middle: gather rows, float4 ----------------
__global__ __launch_bounds__(256) void k_embed_mid(const float* __restrict__ data,
                       const int* __restrict__ unselect,
                       float* __restrict__ X, unsigned short* __restrict__ Xbf) {
  int e = blockIdx.x*256 + threadIdx.x;      // 819200 total
  int r = e >> 5;                            // 0..25599
  int c4 = (e & 31) * 4;
  int b = r / 800, j = r - b*800;
  int nidx = unselect[r];
  const float4 v = *(const float4*)&data[((size_t)b*NN + nidx)*DD + c4];
  size_t off = ((size_t)(b*LQ + 1 + j))*DD + c4;
  *(float4*)&X[off] = v;
  unsigned short p0 = f2bf(v.x), p1 = f2bf(v.y), p2 = f2bf(v.z), p3 = f2bf(v.w);
  ushort4 pk; pk.x = p0; pk.y = p1; pk.z = p2; pk.w = p3;
  *(ushort4*)&Xbf[off] = pk;
}

// ---------------- MFMA QKV: C[M x 384] = Xbf @ [Wq|Wk|Wv] ----------------
__global__ __launch_bounds__(256) void k_qkv_mfma(const unsigned short* __restrict__ Xbf,
                       const unsigned short* __restrict__ Wt,   // [384][128]
                       unsigned short* __restrict__ Qb, unsigned short* __restrict__ Kb,
                       unsigned short* __restrict__ Vb) {
  int row0 = blockIdx.x * 64;
  int t = threadIdx.x, wave = t >> 6, lane = t & 63;
  int col = lane & 31, half = lane >> 5;
  short8 a[2][8];
  const unsigned short* xb = Xbf + (size_t)(row0 + col)*DD + half*8;
  #pragma unroll
  for (int mi = 0; mi < 2; ++mi)
    #pragma unroll
    for (int s = 0; s < 8; ++s)
      a[mi][s] = *(const short8*)(xb + (size_t)mi*32*DD + s*16);
  #pragma unroll
  for (int nn = 0; nn < 3; ++nn) {
    int ni = wave*3 + nn;
    short8 bfr[8];
    const unsigned short* wb = Wt + (size_t)(ni*32 + col)*DD + half*8;
    #pragma unroll
    for (int s = 0; s < 8; ++s) bfr[s] = *(const short8*)(wb + s*16);
    f32x16 acc0 = {0.f,0.f,0.f,0.f,0.f,0.f,0.f,0.f,0.f,0.f,0.f,0.f,0.f,0.f,0.f,0.f};
    f32x16 acc1 = {0.f,0.f,0.f,0.f,0.f,0.f,0.f,0.f,0.f,0.f,0.f,0.f,0.f,0.f,0.f,0.f};
    #pragma unroll
    for (int s = 0; s < 8; ++s) {
      acc0 = __builtin_amdgcn_mfma_f32_32x32x16_bf16(a[0][s], bfr[s], acc0, 0, 0, 0);
      acc1 = __builtin_amdgcn_mfma_f32_32x32x16_bf16(a[1][s], bfr[s], acc1, 0, 0, 0);
    }
    int n = ni*32 + col;
    int sect = n >> 7, nc = n & 127;
    int h = nc >> 4, d = nc & 15;
    #pragma unroll
    for (int mi = 0; mi < 2; ++mi) {
      const f32x16& acc = mi ? acc1 : acc0;
      #pragma unroll
      for (int r = 0; r < 16; ++r) {
        int m = row0 + mi*32 + (r&3) + 8*(r>>2) + 4*half;
        int b_ = m / LQ, l = m - b_*LQ;
        size_t bh = (size_t)(b_*HH + h);
        float v = acc[r];
        if (sect == 0)      Qb[(bh*LQ + l)*DKK + d] = f2bf(v * 0.25f);
        else if (sect == 1) Kb[(bh*LQ + l)*DKK + d] = f2bf(v);
        else                Vb[(bh*LQ + l)*DKK + d] = f2bf(v);
      }
    }
  }
}

// ---------------- flash attention, 64 queries/block, S^T = K·Q^T ----------------
__global__ __launch_bounds__(256) void k_attn3(const unsigned short* __restrict__ Q,
                       const unsigned short* __restrict__ K,
                       const unsigned short* __restrict__ Vb,
                       unsigned short* __restrict__ Obf) {
  int bid = blockIdx.x;
  int g = bid & 7, i = bid >> 3;            // XCD swizzle
  int bhg = i / NQT64, qt = i - bhg*NQT64;
  int bh = bhg*8 + g;
  int b = bh >> 3, h = bh & 7;
  int q0 = qt*64;
  size_t bhLQ = (size_t)bh * LQ;
  int t = threadIdx.x;
  int wave = t >> 6, lane = t & 63;
  int col = lane & 31;
  int half = lane >> 5;
  bool hb = (half != 0);

  __shared__ float mw[2][4][32];
  __shared__ float sw[2][4][32];
  __shared__ float sfin[2][32];
  __shared__ float ored[2][4][16][32];      // 16 KB
  __shared__ float osum[2][32][17];

  // B-frags for the two query subtiles
  int q0c = q0 + col;      if (q0c > LQ-1) q0c = LQ-1;
  int q1c = q0 + 32 + col; if (q1c > LQ-1) q1c = LQ-1;
  short8 bQ0 = *(const short8*)&Q[(bhLQ + q0c)*DKK + half*8];
  short8 bQ1 = *(const short8*)&Q[(bhLQ + q1c)*DKK + half*8];

  f32x16 oacc0 = {0.f,0.f,0.f,0.f,0.f,0.f,0.f,0.f,0.f,0.f,0.f,0.f,0.f,0.f,0.f,0.f};
  f32x16 oacc1 = oacc0;
  float runm0 = -INFINITY, runs0 = 0.f;
  float runm1 = -INFINITY, runs1 = 0.f;

  for (int kt = wave; kt < NQT; kt += 4) {
    int key0 = kt*32;
    int keyA = key0 + col; if (keyA > LQ-1) keyA = LQ-1;
    short8 aK = *(const short8*)&K[(bhLQ + keyA)*DKK + half*8];
    // V A-frags: lane m=col (dv<16), k = half*8+j ; row-major gather (32B/step coalesced)
    short8 aV0 = {0,0,0,0,0,0,0,0};
    short8 aV1 = {0,0,0,0,0,0,0,0};
    if (col < 16) {
      const unsigned short* vbase = Vb + bhLQ*DKK + col;
      #pragma unroll
      for (int j = 0; j < 8; ++j) {
        int k1 = key0 + half*8 + j;      if (k1 > LQ-1) k1 = LQ-1;
        int k2 = key0 + 16 + half*8 + j; if (k2 > LQ-1) k2 = LQ-1;
        aV0[j] = (short)vbase[(size_t)k1*DKK];
        aV1[j] = (short)vbase[(size_t)k2*DKK];
      }
    }
    bool full = (key0 + 31 < LQ);

    auto process = [&](const short8& bQ, f32x16& oacc, float& runm, float& runs) {
      f32x16 c = {0.f,0.f,0.f,0.f,0.f,0.f,0.f,0.f,0.f,0.f,0.f,0.f,0.f,0.f,0.f,0.f};
      c = __builtin_amdgcn_mfma_f32_32x32x16_bf16(aK, bQ, c, 0, 0, 0);
      float tm;
      if (full) {
        tm = c[0];
        #pragma unroll
        for (int r = 1; r < 16; ++r) tm = fmaxf(tm, c[r]);
      } else {
        tm = -INFINITY;
        #pragma unroll
        for (int r = 0; r < 16; ++r) {
          int key = key0 + (r&3) + 8*(r>>2) + 4*half;
          if (key < LQ) tm = fmaxf(tm, c[r]);
        }
      }
      tm = fmaxf(tm, __shfl_xor(tm, 32, 64));   // half-pair consistent scale
      float mnew = fmaxf(runm, tm);
      float scale = __expf(runm - mnew);
      runs *= scale;
      #pragma unroll
      for (int r = 0; r < 8; ++r) oacc[r] *= scale;  // only rows<16 are live (PV A-rows 16..31 = 0)
      runm = mnew;
      float p[16];
      if (full) {
        #pragma unroll
        for (int r = 0; r < 16; ++r) p[r] = __expf(c[r] - mnew);
      } else {
        #pragma unroll
        for (int r = 0; r < 16; ++r) {
          int key = key0 + (r&3) + 8*(r>>2) + 4*half;
          p[r] = (key < LQ) ? __expf(c[r] - mnew) : 0.f;
        }
      }
      float ts = 0.f;
      #pragma unroll
      for (int r = 0; r < 16; ++r) ts += p[r];
      runs += ts;
      unsigned int pk[8];
      #pragma unroll
      for (int j = 0; j < 8; ++j) {
        unsigned int ua = __float_as_uint(p[2*j]);
        unsigned int ub = __float_as_uint(p[2*j+1]);
        pk[j] = (ua >> 16) | (ub & 0xffff0000u);
      }
      int Y0 = __shfl_xor((int)(hb ? pk[0] : pk[2]), 32, 64);
      int Y1 = __shfl_xor((int)(hb ? pk[1] : pk[3]), 32, 64);
      int Y2 = __shfl_xor((int)(hb ? pk[4] : pk[6]), 32, 64);
      int Y3 = __shfl_xor((int)(hb ? pk[5] : pk[7]), 32, 64);
      union { int4 i4; short8 s8; } fA, fB;
      fA.i4.x = hb ? Y0 : (int)pk[0];
      fA.i4.y = hb ? Y1 : (int)pk[1];
      fA.i4.z = hb ? (int)pk[2] : Y0;
      fA.i4.w = hb ? (int)pk[3] : Y1;
      fB.i4.x = hb ? Y2 : (int)pk[4];
      fB.i4.y = hb ? Y3 : (int)pk[5];
      fB.i4.z = hb ? (int)pk[6] : Y2;
      fB.i4.w = hb ? (int)pk[7] : Y3;
      oacc = __builtin_amdgcn_mfma_f32_32x32x16_bf16(aV0, fA.s8, oacc, 0, 0, 0);
      oacc = __builtin_amdgcn_mfma_f32_32x32x16_bf16(aV1, fB.s8, oacc, 0, 0, 0);
    };
    process(bQ0, oacc0, runm0, runs0);
    process(bQ1, oacc1, runm1, runs1);
  }

  // ---- merge halves, then waves, for both subtiles ----
  float m2v[2], fsv[2];
  #pragma unroll
  for (int u = 0; u < 2; ++u) {
    float runm = u ? runm1 : runm0;
    float runs = u ? runs1 : runs0;
    float pm = __shfl_xor(runm, 32, 64);
    float ps = __shfl_xor(runs, 32, 64);
    float m2 = fmaxf(runm, pm);
    float fself = __expf(runm - m2);
    float s2 = runs*fself + ps*__expf(pm - m2);
    if (half == 0) { mw[u][wave][col] = m2; sw[u][wave][col] = s2; }
    m2v[u] = m2; fsv[u] = fself;
  }
  __syncthreads();
  #pragma unroll
  for (int u = 0; u < 2; ++u) {
    float M = fmaxf(fmaxf(mw[u][0][col], mw[u][1][col]), fmaxf(mw[u][2][col], mw[u][3][col]));
    float S = sw[u][0][col]*__expf(mw[u][0][col]-M) + sw[u][1][col]*__expf(mw[u][1][col]-M)
            + sw[u][2][col]*__expf(mw[u][2][col]-M) + sw[u][3][col]*__expf(mw[u][3][col]-M);
    float fw = __expf(m2v[u] - M) * fsv[u];
    const f32x16& oacc = u ? oacc1 : oacc0;
    #pragma unroll
    for (int r = 0; r < 8; ++r) {
      int dv = (r&3) + 8*(r>>2) + 4*half;
      ored[u][wave][dv][col] = oacc[r] * fw;
    }
    if (wave == 0 && half == 0) sfin[u][col] = S;
  }
  __syncthreads();
  {
    int qq = t & 31, dv0 = t >> 5;
    #pragma unroll
    for (int u = 0; u < 2; ++u)
      #pragma unroll
      for (int k = 0; k < 2; ++k) {
        int dv = dv0 + 8*k;
        osum[u][qq][dv] = ored[u][0][dv][qq] + ored[u][1][dv][qq]
                        + ored[u][2][dv][qq] + ored[u][3][dv][qq];
      }
  }
  __syncthreads();
  {
    int qs = t >> 3, c2 = (t & 7)*2;
    #pragma unroll
    for (int u = 0; u < 2; ++u) {
      int q = q0 + u*32 + qs;
      if (q < LQ) {
        float invS = 1.f / sfin[u][qs];
        unsigned int lo = f2bf(osum[u][qs][c2]   * invS);
        unsigned int hi = f2bf(osum[u][qs][c2+1] * invS);
        *(unsigned int*)&Obf[((size_t)(b*LQ + q))*DD + h*DKK + c2] = lo | (hi << 16);
      }
    }
  }
}

// ---------------- fused proj + FF: X = out1 + ff(out1), out1 = X + Obf@Wo + bo ----------------
__global__ __launch_bounds__(256) void k_pff(const unsigned short* __restrict__ Obf,
        const unsigned short* __restrict__ Wot, const float* __restrict__ bo,
        const unsigned short* __restrict__ W1t, const float* __restrict__ b1,
        const unsigned short* __restrict__ W2t, const float* __restrict__ b2,
        float* __restrict__ X, unsigned short* __restrict__ Xbf) {
  __shared__ __align__(16) unsigned short LDSU[64 * HSTR];   // 66048 B, union T/Hs
  unsigned short* T  = LDSU;   // [64][TSTR] out1 bf16 tile
  unsigned short* Hs = LDSU;   // [64][HSTR] hidden tile (after T consumed)
  int row0 = blockIdx.x * 64;
  int t = threadIdx.x, wave = t >> 6, lane = t & 63;
  int col = lane & 31, half = lane >> 5;
  int n = wave*32 + col;
  // ---- phase P: proj ----
  float res[2][16];
  {
    short8 a[2][8];
    const unsigned short* ob = Obf + (size_t)(row0 + col)*DD + half*8;
    #pragma unroll
    for (int mi = 0; mi < 2; ++mi)
      #pragma unroll
      for (int s = 0; s < 8; ++s)
        a[mi][s] = *(const short8*)(ob + (size_t)mi*32*DD + s*16);
    short8 bfr[8];
    const unsigned short* wb = Wot + (size_t)n*DD + half*8;
    #pragma unroll
    for (int s = 0; s < 8; ++s) bfr[s] = *(const short8*)(wb + s*16);
    f32x16 acc0 = {0.f,0.f,0.f,0.f,0.f,0.f,0.f,0.f,0.f,0.f,0.f,0.f,0.f,0.f,0.f,0.f};
    f32x16 acc1 = acc0;
    #pragma unroll
    for (int s = 0; s < 8; ++s) {
      acc0 = __builtin_amdgcn_mfma_f32_32x32x16_bf16(a[0][s], bfr[s], acc0, 0, 0, 0);
      acc1 = __builtin_amdgcn_mfma_f32_32x32x16_bf16(a[1][s], bfr[s], acc1, 0, 0, 0);
    }
    float bv = bo[n];
    #pragma unroll
    for (int mi = 0; mi < 2; ++mi) {
      const f32x16& acc = mi ? acc1 : acc0;
      #pragma unroll
      for (int r = 0; r < 16; ++r) {
        int ml = mi*32 + (r&3) + 8*(r>>2) + 4*half;
        size_t off = (size_t)(row0 + ml)*DD + n;
        res[mi][r] = X[off] + acc[r] + bv;
        T[ml*TSTR + n] = f2bf(res[mi][r]);
      }
    }
  }
  __syncthreads();
  // ---- preload F1 A-frags from T (b64 pairs; TSTR -> 2-way alias, free) ----
  short8 aF[2][8];
  #pragma unroll
  for (int mi = 0; mi < 2; ++mi)
    #pragma unroll
    for (int s = 0; s < 8; ++s) {
      const unsigned short* tp = &T[(mi*32 + col)*TSTR + half*8 + s*16];
      union { short4v h[2]; short8 v; } u;
      u.h[0] = *(const short4v*)tp;
      u.h[1] = *(const short4v*)(tp + 4);
      aF[mi][s] = u.v;
    }
  __syncthreads();   // T fully read; Hs may overwrite
  // ---- phase F1: H = relu(out1 @ W1 + b1) -> LDS ----
  #pragma unroll
  for (int nn = 0; nn < 4; ++nn) {
    int ni = wave*4 + nn;
    short8 bfr[8];
    const unsigned short* wb = W1t + (size_t)(ni*32 + col)*DD + half*8;
    #pragma unroll
    for (int s = 0; s < 8; ++s) bfr[s] = *(const short8*)(wb + s*16);
    f32x16 acc0 = {0.f,0.f,0.f,0.f,0.f,0.f,0.f,0.f,0.f,0.f,0.f,0.f,0.f,0.f,0.f,0.f};
    f32x16 acc1 = acc0;
    #pragma unroll
    for (int s = 0; s < 8; ++s) {
      acc0 = __builtin_amdgcn_mfma_f32_32x32x16_bf16(aF[0][s], bfr[s], acc0, 0, 0, 0);
      acc1 = __builtin_amdgcn_mfma_f32_32x32x16_bf16(aF[1][s], bfr[s], acc1, 0, 0, 0);
    }
    int nf = ni*32 + col;
    float bv = b1[nf];
    #pragma unroll
    for (int mi = 0; mi < 2; ++mi) {
      const f32x16& acc = mi ? acc1 : acc0;
      #pragma unroll
      for (int r = 0; r < 16; ++r) {
        int ml = mi*32 + (r&3) + 8*(r>>2) + 4*half;
        Hs[ml*HSTR + nf] = f2bf(fmaxf(acc[r] + bv, 0.f));
      }
    }
  }
  __syncthreads();
  // ---- phase F2: C = H @ W2 (K=512) + residual epilogue ----
  f32x16 acc0 = {0.f,0.f,0.f,0.f,0.f,0.f,0.f,0.f,0.f,0.f,0.f,0.f,0.f,0.f,0.f,0.f};
  f32x16 acc1 = acc0;
  const unsigned short* w2b = W2t + (size_t)n*FFD + half*8;
  #pragma unroll 4
  for (int s = 0; s < 32; ++s) {
    int ko = s*16 + half*8;
    union { short4v h[2]; short8 v; } h0, h1;
    const unsigned short* hp0 = &Hs[col*HSTR + ko];
    const unsigned short* hp1 = &Hs[(32 + col)*HSTR + ko];
    h0.h[0] = *(const short4v*)hp0;  h0.h[1] = *(const short4v*)(hp0 + 4);
    h1.h[0] = *(const short4v*)hp1;  h1.h[1] = *(const short4v*)(hp1 + 4);
    short8 bfr = *(const short8*)(w2b + s*16);
    acc0 = __builtin_amdgcn_mfma_f32_32x32x16_bf16(h0.v, bfr, acc0, 0, 0, 0);
    acc1 = __builtin_amdgcn_mfma_f32_32x32x16_bf16(h1.v, bfr, acc1, 0, 0, 0);
  }
  float bv = b2[n];
  #pragma unroll
  for (int mi = 0; mi < 2; ++mi) {
    const f32x16& acc = mi ? acc1 : acc0;
    #pragma unroll
    for (int r = 0; r < 16; ++r) {
      int ml = mi*32 + (r&3) + 8*(r>>2) + 4*half;
      size_t off = (size_t)(row0 + ml)*DD + n;
      float v = res[mi][r] + acc[r] + bv;
      X[off] = v;
      Xbf[off] = f2bf(v);
    }
  }
}

// ---------------- logits: one wave per row ----------------
__global__ __launch_bounds__(256) void k_logits(const float* __restrict__ X,
                        const float* __restrict__ Wfin, const float* __restrict__ bfin,
                        float* __restrict__ logits) {
  int t = threadIdx.x, wave = t >> 6, lane = t & 63;
  int row = blockIdx.x*4 + wave;            // 6416*4 = 25664 exact
  float2 xv = *(const float2*)&X[(size_t)row*DD + lane*2];
  float2 wv = *(const float2*)&Wfin[lane*2];
  float v = xv.x*wv.x + xv.y*wv.y;
  #pragma unroll
  for (int off = 32; off > 0; off >>= 1) v += __shfl_down(v, off);
  if (lane == 0) logits[row] = v + bfin[0];
}

// ---------------- bias add, softmax, epsilon, scatter ----------------
__global__ __launch_bounds__(256) void k_final(const float* __restrict__ logits,
                       const float* __restrict__ AB, const int* __restrict__ sel,
                       const int* __restrict__ unselect, const int* __restrict__ pos,
                       float* __restrict__ out) {
  int b = blockIdx.x, t = threadIdx.x;
  __shared__ float sl[800];
  __shared__ float red[256];
  int lastsel = sel[b*SS + SS-1];
  const float* abrow = AB + ((size_t)b*NN + lastsel)*NN;
  for (int j = t; j < 800; j += 256)
    sl[j] = logits[b*LQ + j + 1] + abrow[unselect[b*800 + j]];
  __syncthreads();
  float lm = -INFINITY;
  for (int j = t; j < 800; j += 256) lm = fmaxf(lm, sl[j]);
  red[t] = lm;
  __syncthreads();
  for (int s = 128; s > 0; s >>= 1) {
    if (t < s) red[t] = fmaxf(red[t], red[t+s]);
    __syncthreads();
  }
  float m = red[0];
  __syncthreads();
  float ls = 0.f;
  for (int j = t; j < 800; j += 256) ls += __expf(sl[j] - m);
  red[t] = ls;
  __syncthreads();
  for (int s = 128; s > 0; s >>= 1) {
    if (t < s) red[t] += red[t+s];
    __syncthreads();
  }
  float inv = 1.f / red[0];
  for (int n = t; n < NN; n += 256) {
    int p1 = pos[b*NN + n];
    float v = -2.0f;
    if (p1 >= 0) {
      float p = __expf(sl[p1-1] - m) * inv;
      if (p <= 1e-5f) p += 1e-7f;
      v = p;
    }
    out[(size_t)b*NN + n] = v;
  }
}

extern "C" void kernel_launch(void* const* d_in, const int* in_sizes, int n_in,
                              void* d_out, int out_size, void* d_ws, size_t ws_size,
                              hipStream_t stream) {
  const float* data   = (const float*)d_in[0];
  const float* AB     = (const float*)d_in[1];
  const float* Wfirst = (const float*)d_in[2];
  const float* bfirst = (const float*)d_in[3];
  const float* Wlast  = (const float*)d_in[4];
  const float* blast  = (const float*)d_in[5];
  const float* Wq     = (const float*)d_in[6];
  const float* Wk     = (const float*)d_in[7];
  const float* Wv     = (const float*)d_in[8];
  const float* Wo     = (const float*)d_in[9];
  const float* bo     = (const float*)d_in[10];
  const float* W1     = (const float*)d_in[11];
  const float* b1     = (const float*)d_in[12];
  const float* W2     = (const float*)d_in[13];
  const float* b2     = (const float*)d_in[14];
  const float* Wfin   = (const float*)d_in[15];
  const float* bfin   = (const float*)d_in[16];
  const int*   sel    = (const int*)d_in[17];
  float* out = (float*)d_out;
  (void)in_sizes; (void)n_in; (void)out_size; (void)ws_size;

  char* ws = (char*)d_ws;
  const size_t NELT = (size_t)MROWS * DD;       // 3,284,992
  int*   UNSEL = (int*)ws;                      // 102,400 B
  int*   POS   = (int*)(ws + 102400);           // ends 230,400
  float* X     = (float*)(ws + 230400);
  unsigned short* Xbf = (unsigned short*)(X + NELT);
  unsigned short* Ob  = Xbf + NELT;
  unsigned short* Qb  = Ob + NELT;
  unsigned short* Kb  = Qb + (size_t)NB*HH*LQ*DKK;
  unsigned short* Vb  = Kb + (size_t)NB*HH*LQ*DKK;
  unsigned short* WtQKV = Vb + (size_t)NB*HH*LQ*DKK;
  unsigned short* Wot = WtQKV + (size_t)NLAYER*384*128;
  unsigned short* W1t = Wot + (size_t)NLAYER*128*128;
  unsigned short* W2t = W1t + (size_t)NLAYER*512*128;
  float* LOG = (float*)(W2t + (size_t)NLAYER*128*512);

  k_wconv<<<(3*WCH + 255)/256, 256, 0, stream>>>(Wq, Wk, Wv, Wo, W1, W2, WtQKV, Wot, W1t, W2t);
  k_unselect<<<NB, 1024, 0, stream>>>(sel, UNSEL, POS);
  k_embed_ends<<<dim3(2, NB), 128, 0, stream>>>(data, sel, Wfirst, bfirst, Wlast, blast, X, Xbf);
  k_embed_mid<<<3200, 256, 0, stream>>>(data, UNSEL, X, Xbf);
  for (int i = 0; i < NLAYER; ++i) {
    k_qkv_mfma<<<NBLK64, 256, 0, stream>>>(Xbf, WtQKV + (size_t)i*384*128, Qb, Kb, Vb);
    k_attn3<<<NQT64*HH*NB, 256, 0, stream>>>(Qb, Kb, Vb, Ob);
    k_pff<<<NBLK64, 256, 0, stream>>>(Ob, Wot + (size_t)i*128*128, bo + (size_t)i*DD,
                                      W1t + (size_t)i*512*128, b1 + (size_t)i*FFD,
                                      W2t + (size_t)i*128*512, b2 + (size_t)i*DD, X, Xbf);
  }
  k_logits<<<MROWS/4, 256, 0, stream>>>(X, Wfin, bfin, LOG);
  k_final<<<NB, 256, 0, stream>>>(LOG, AB, sel, UNSEL, POS, out);
}

// Round 7
// 560.846 us; speedup vs baseline: 3.5864x; 1.0212x over previous
//
#include <hip/hip_runtime.h>
#include <hip/hip_bf16.h>
#include <math.h>

#define NB 32
#define NN 1000
#define SS 200
#define DD 128
#define HH 8
#define DKK 16
#define FFD 512
#define NLAYER 3
#define LQ 802
#define LPAD 832           // padded key/query count (26 tiles of 32); pads are exact zeros
#define NPADK (LPAD - LQ)  // 30 pad keys -> contribute exactly 30*e^{-M} to denominator
#define MROWS (NB*LQ)      // 25664
#define NBLK64 (MROWS/64)  // 401 exactly
#define NQT 26             // key tiles of 32 (all full after padding)
#define NQT64 13           // query tiles of 64
#define HSTR 516           // H LDS stride (shorts): 2-bank step -> 2-way alias = free
#define TSTR 132           // T LDS stride (shorts): 2-bank step -> 2-way alias = free

typedef __attribute__((ext_vector_type(8))) short short8;
typedef __attribute__((ext_vector_type(4))) short short4v;
typedef __attribute__((ext_vector_type(16))) float f32x16;

static __device__ __forceinline__ unsigned short f2bf(float x) {
  union { float f; unsigned int u; } v; v.f = x;
  unsigned int r = v.u + 0x7fff + ((v.u >> 16) & 1);   // RNE
  return (unsigned short)(r >> 16);
}

// ---------------- weight transpose+convert: W[k][n] fp32 -> Wt[n][k] bf16 ----------------
#define WCH 196608         // per-layer: 49152+16384+65536+65536
__global__ __launch_bounds__(256) void k_wconv(const float* __restrict__ Wq, const float* __restrict__ Wk,
                       const float* __restrict__ Wv, const float* __restrict__ Wo,
                       const float* __restrict__ W1, const float* __restrict__ W2,
                       unsigned short* __restrict__ WtQKV, unsigned short* __restrict__ Wot,
                       unsigned short* __restrict__ W1t, unsigned short* __restrict__ W2t) {
  int e = blockIdx.x*256 + threadIdx.x;
  if (e >= 3*WCH) return;
  int layer = e / WCH, r = e - layer*WCH;
  if (r < 49152) {
    int n = r >> 7, k = r & 127;
    int sect = n >> 7, nn = n & 127;
    const float* W = (sect == 0) ? Wq : (sect == 1) ? Wk : Wv;
    WtQKV[layer*49152 + r] = f2bf(W[layer*16384 + k*128 + nn]);
  } else if (r < 65536) {
    int r2 = r - 49152;
    int n = r2 >> 7, k = r2 & 127;
    Wot[layer*16384 + r2] = f2bf(Wo[layer*16384 + k*128 + n]);
  } else if (r < 131072) {
    int r2 = r - 65536;
    int n = r2 >> 7, k = r2 & 127;
    W1t[layer*65536 + r2] = f2bf(W1[layer*65536 + k*512 + n]);
  } else {
    int r2 = r - 131072;
    int n = r2 >> 9, k = r2 & 511;
    W2t[layer*65536 + r2] = f2bf(W2[layer*65536 + k*128 + n]);
  }
}

// ---------------- unselect + pos (inverse map) ----------------
__global__ __launch_bounds__(1024) void k_unselect(const int* __restrict__ sel,
                                                   int* __restrict__ unselect,
                                                   int* __restrict__ pos) {
  int b = blockIdx.x;
  int n = threadIdx.x;
  __shared__ int bufA[1024];
  __shared__ int bufB[1024];
  bufA[n] = (n < NN) ? 1 : 0;
  __syncthreads();
  if (n < SS) bufA[sel[b*SS + n]] = 0;
  __syncthreads();
  int flag = bufA[n];
  int* src = bufA; int* dst = bufB;
  for (int off = 1; off < 1024; off <<= 1) {
    int v = src[n];
    if (n >= off) v += src[n - off];
    __syncthreads();
    dst[n] = v;
    __syncthreads();
    int* tp = src; src = dst; dst = tp;
  }
  if (n < NN) {
    if (flag) {
      int j = src[n] - 1;
      unselect[b*800 + j] = n;
      pos[b*NN + n] = j + 1;
    } else {
      pos[b*NN + n] = -1;
    }
  }
}

// ---------------- X ends: rows 0 and LQ-1 (matvec) ----------------
__global__ __launch_bounds__(128) void k_embed_ends(const float* __restrict__ data,
                       const int* __restrict__ sel,
                       const float* __restrict__ Wfirst, const float* __restrict__ bfirst,
                       const float* __restrict__ Wlast, const float* __restrict__ blast,
                       float* __restrict__ X, unsigned short* __restrict__ Xbf) {
  int which = blockIdx.x, b = blockIdx.y, d = threadIdx.x;
  int l = (which == 0) ? 0 : LQ-1;
  __shared__ float xr[DD];
  int src = sel[b*SS + (which == 0 ? 0 : SS-1)];
  const float* W    = (which == 0) ? Wfirst : Wlast;
  const float* bias = (which == 0) ? bfirst : blast;
  xr[d] = data[((size_t)b*NN + src)*DD + d];
  __syncthreads();
  float acc = bias[d];
  #pragma unroll 4
  for (int k = 0; k < DD; ++k) acc += xr[k] * W[k*DD + d];
  size_t off = ((size_t)(b*LQ + l))*DD + d;
  X[off] = acc;
  Xbf[off] = f2bf(acc);
}

// ---------------- X middle: gather rows, float4 ----------------
__global__ __launch_bounds__(256) void k_embed_mid(const float* __restrict__ data,
                       const int* __restrict__ unselect,
                       float* __restrict__ X, unsigned short* __restrict__ Xbf) {
  int e = blockIdx.x*256 + threadIdx.x;      // 819200 total
  int r = e >> 5;                            // 0..25599
  int c4 = (e & 31) * 4;
  int b = r / 800, j = r - b*800;
  int nidx = unselect[r];
  const float4 v = *(const float4*)&data[((size_t)b*NN + nidx)*DD + c4];
  size_t off = ((size_t)(b*LQ + 1 + j))*DD + c4;
  *(float4*)&X[off] = v;
  unsigned short p0 = f2bf(v.x), p1 = f2bf(v.y), p2 = f2bf(v.z), p3 = f2bf(v.w);
  ushort4 pk; pk.x = p0; pk.y = p1; pk.z = p2; pk.w = p3;
  *(ushort4*)&Xbf[off] = pk;
}

// ---------------- MFMA QKV: C[M x 384] = Xbf @ [Wq|Wk|Wv]; row-major Q/K/V [bh][LPAD][dk] ----------------
__global__ __launch_bounds__(256) void k_qkv_mfma(const unsigned short* __restrict__ Xbf,
                       const unsigned short* __restrict__ Wt,   // [384][128]
                       unsigned short* __restrict__ Qb, unsigned short* __restrict__ Kb,
                       unsigned short* __restrict__ Vb) {
  int row0 = blockIdx.x * 64;
  int t = threadIdx.x, wave = t >> 6, lane = t & 63;
  int col = lane & 31, half = lane >> 5;
  short8 a[2][8];
  const unsigned short* xb = Xbf + (size_t)(row0 + col)*DD + half*8;
  #pragma unroll
  for (int mi = 0; mi < 2; ++mi)
    #pragma unroll
    for (int s = 0; s < 8; ++s)
      a[mi][s] = *(const short8*)(xb + (size_t)mi*32*DD + s*16);
  #pragma unroll
  for (int nn = 0; nn < 3; ++nn) {
    int ni = wave*3 + nn;
    short8 bfr[8];
    const unsigned short* wb = Wt + (size_t)(ni*32 + col)*DD + half*8;
    #pragma unroll
    for (int s = 0; s < 8; ++s) bfr[s] = *(const short8*)(wb + s*16);
    f32x16 acc0 = {0.f,0.f,0.f,0.f,0.f,0.f,0.f,0.f,0.f,0.f,0.f,0.f,0.f,0.f,0.f,0.f};
    f32x16 acc1 = {0.f,0.f,0.f,0.f,0.f,0.f,0.f,0.f,0.f,0.f,0.f,0.f,0.f,0.f,0.f,0.f};
    #pragma unroll
    for (int s = 0; s < 8; ++s) {
      acc0 = __builtin_amdgcn_mfma_f32_32x32x16_bf16(a[0][s], bfr[s], acc0, 0, 0, 0);
      acc1 = __builtin_amdgcn_mfma_f32_32x32x16_bf16(a[1][s], bfr[s], acc1, 0, 0, 0);
    }
    int n = ni*32 + col;
    int sect = n >> 7, nc = n & 127;
    int h = nc >> 4, d = nc & 15;
    #pragma unroll
    for (int mi = 0; mi < 2; ++mi) {
      const f32x16& acc = mi ? acc1 : acc0;
      #pragma unroll
      for (int r = 0; r < 16; ++r) {
        int m = row0 + mi*32 + (r&3) + 8*(r>>2) + 4*half;
        int b_ = m / LQ, l = m - b_*LQ;
        size_t bh = (size_t)(b_*HH + h);
        float v = acc[r];
        if (sect == 0)      Qb[(bh*LPAD + l)*DKK + d] = f2bf(v * 0.25f);
        else if (sect == 1) Kb[(bh*LPAD + l)*DKK + d] = f2bf(v);
        else                Vb[(bh*LPAD + l)*DKK + d] = f2bf(v);
      }
    }
  }
}

// ---------------- V transpose (LDS-tiled) + zero pads of Vt and Kb ----------------
__global__ __launch_bounds__(256) void k_vt(const unsigned short* __restrict__ Vb,  // [bh][LPAD][16]
                                            unsigned short* __restrict__ Vt,        // [bh][16][LPAD]
                                            unsigned short* __restrict__ Kb) {
  __shared__ unsigned short Lt[16][72];
  int l0 = blockIdx.x * 64;                 // 13 tiles cover 832
  int bh = blockIdx.y;
  int t = threadIdx.x;
  int l = t >> 2, d4 = (t & 3) * 4;
  ushort4 v = {0,0,0,0};
  if (l0 + l < LQ) v = *(const ushort4*)&Vb[((size_t)bh*LPAD + l0 + l)*DKK + d4];
  Lt[d4+0][l] = v.x; Lt[d4+1][l] = v.y; Lt[d4+2][l] = v.z; Lt[d4+3][l] = v.w;
  __syncthreads();
  int dk = t >> 4, lq = (t & 15)*4;
  ushort4 o;
  o.x = Lt[dk][lq]; o.y = Lt[dk][lq+1]; o.z = Lt[dk][lq+2]; o.w = Lt[dk][lq+3];
  *(ushort4*)&Vt[((size_t)bh*DKK + dk)*LPAD + l0 + lq] = o;
  if (blockIdx.x == 12 && t < 240)          // zero Kb pad rows (30 rows * 16 dk = 240 uints)
    ((unsigned int*)&Kb[((size_t)bh*LPAD + LQ)*DKK])[t] = 0u;
}

// ---------------- flash attention, 64 queries/block, S^T = K·Q^T, padded keys ----------------
// Pads (K rows = 0) give exact score 0 -> denominator over-counts by NPADK*e^{-M},
// subtracted analytically in the final merge. No bounds checks in the K-loop.
__global__ __launch_bounds__(256) void k_attn3(const unsigned short* __restrict__ Q,
                       const unsigned short* __restrict__ K,
                       const unsigned short* __restrict__ Vt,
                       unsigned short* __restrict__ Obf) {
  int bid = blockIdx.x;
  int g = bid & 7, i = bid >> 3;            // XCD swizzle
  int bhg = i / NQT64, qt = i - bhg*NQT64;
  int bh = bhg*8 + g;
  int b = bh >> 3, h = bh & 7;
  int q0 = qt*64;
  size_t bhL = (size_t)bh * LPAD;
  int t = threadIdx.x;
  int wave = t >> 6, lane = t & 63;
  int col = lane & 31;
  int half = lane >> 5;
  bool hb = (half != 0);

  __shared__ float mw[2][4][32];
  __shared__ float sw[2][4][32];
  __shared__ float sfin[2][32];
  __shared__ float ored[2][4][16][32];      // 16 KB
  __shared__ float osum[2][32][17];

  int q0c = q0 + col;      if (q0c > LQ-1) q0c = LQ-1;
  int q1c = q0 + 32 + col; if (q1c > LQ-1) q1c = LQ-1;
  short8 bQ0 = *(const short8*)&Q[(bhL + q0c)*DKK + half*8];
  short8 bQ1 = *(const short8*)&Q[(bhL + q1c)*DKK + half*8];

  f32x16 oacc0 = {0.f,0.f,0.f,0.f,0.f,0.f,0.f,0.f,0.f,0.f,0.f,0.f,0.f,0.f,0.f,0.f};
  f32x16 oacc1 = oacc0;
  float runm0 = -INFINITY, runs0 = 0.f;
  float runm1 = -INFINITY, runs1 = 0.f;

  for (int kt = wave; kt < NQT; kt += 4) {
    int key0 = kt*32;
    short8 aK = *(const short8*)&K[(bhL + key0 + col)*DKK + half*8];
    short8 aV0 = {0,0,0,0,0,0,0,0};
    short8 aV1 = {0,0,0,0,0,0,0,0};
    if (col < 16) {
      const unsigned short* vp = &Vt[((size_t)bh*DKK + col)*LPAD + key0 + half*8];
      aV0 = *(const short8*)vp;
      aV1 = *(const short8*)(vp + 16);
    }

    auto process = [&](const short8& bQ, f32x16& oacc, float& runm, float& runs) {
      f32x16 c = {0.f,0.f,0.f,0.f,0.f,0.f,0.f,0.f,0.f,0.f,0.f,0.f,0.f,0.f,0.f,0.f};
      c = __builtin_amdgcn_mfma_f32_32x32x16_bf16(aK, bQ, c, 0, 0, 0);
      float tm = c[0];
      #pragma unroll
      for (int r = 1; r < 16; ++r) tm = fmaxf(tm, c[r]);
      tm = fmaxf(tm, __shfl_xor(tm, 32, 64));   // half-pair consistent scale
      float mnew = fmaxf(runm, tm);
      float scale = __expf(runm - mnew);
      runs *= scale;
      #pragma unroll
      for (int r = 0; r < 8; ++r) oacc[r] *= scale;
      runm = mnew;
      float p[16];
      #pragma unroll
      for (int r = 0; r < 16; ++r) p[r] = __expf(c[r] - mnew);
      float ts = 0.f;
      #pragma unroll
      for (int r = 0; r < 16; ++r) ts += p[r];
      runs += ts;
      unsigned int pk[8];
      #pragma unroll
      for (int j = 0; j < 8; ++j) {
        unsigned int ua = __float_as_uint(p[2*j]);
        unsigned int ub = __float_as_uint(p[2*j+1]);
        pk[j] = (ua >> 16) | (ub & 0xffff0000u);
      }
      int Y0 = __shfl_xor((int)(hb ? pk[0] : pk[2]), 32, 64);
      int Y1 = __shfl_xor((int)(hb ? pk[1] : pk[3]), 32, 64);
      int Y2 = __shfl_xor((int)(hb ? pk[4] : pk[6]), 32, 64);
      int Y3 = __shfl_xor((int)(hb ? pk[5] : pk[7]), 32, 64);
      union { int4 i4; short8 s8; } fA, fB;
      fA.i4.x = hb ? Y0 : (int)pk[0];
      fA.i4.y = hb ? Y1 : (int)pk[1];
      fA.i4.z = hb ? (int)pk[2] : Y0;
      fA.i4.w = hb ? (int)pk[3] : Y1;
      fB.i4.x = hb ? Y2 : (int)pk[4];
      fB.i4.y = hb ? Y3 : (int)pk[5];
      fB.i4.z = hb ? (int)pk[6] : Y2;
      fB.i4.w = hb ? (int)pk[7] : Y3;
      oacc = __builtin_amdgcn_mfma_f32_32x32x16_bf16(aV0, fA.s8, oacc, 0, 0, 0);
      oacc = __builtin_amdgcn_mfma_f32_32x32x16_bf16(aV1, fB.s8, oacc, 0, 0, 0);
    };
    process(bQ0, oacc0, runm0, runs0);
    process(bQ1, oacc1, runm1, runs1);
  }

  // ---- merge halves, then waves ----
  float m2v[2], fsv[2];
  #pragma unroll
  for (int u = 0; u < 2; ++u) {
    float runm = u ? runm1 : runm0;
    float runs = u ? runs1 : runs0;
    float pm = __shfl_xor(runm, 32, 64);
    float ps = __shfl_xor(runs, 32, 64);
    float m2 = fmaxf(runm, pm);
    float fself = __expf(runm - m2);
    float s2 = runs*fself + ps*__expf(pm - m2);
    if (half == 0) { mw[u][wave][col] = m2; sw[u][wave][col] = s2; }
    m2v[u] = m2; fsv[u] = fself;
  }
  __syncthreads();
  #pragma unroll
  for (int u = 0; u < 2; ++u) {
    float M = fmaxf(fmaxf(mw[u][0][col], mw[u][1][col]), fmaxf(mw[u][2][col], mw[u][3][col]));
    float S = sw[u][0][col]*__expf(mw[u][0][col]-M) + sw[u][1][col]*__expf(mw[u][1][col]-M)
            + sw[u][2][col]*__expf(mw[u][2][col]-M) + sw[u][3][col]*__expf(mw[u][3][col]-M);
    float fw = __expf(m2v[u] - M) * fsv[u];
    const f32x16& oacc = u ? oacc1 : oacc0;
    #pragma unroll
    for (int r = 0; r < 8; ++r) {
      int dv = (r&3) + 8*(r>>2) + 4*half;
      ored[u][wave][dv][col] = oacc[r] * fw;
    }
    if (wave == 0 && half == 0)
      sfin[u][col] = S - (float)NPADK * __expf(-M);   // remove exact pad mass
  }
  __syncthreads();
  {
    int qq = t & 31, dv0 = t >> 5;
    #pragma unroll
    for (int u = 0; u < 2; ++u)
      #pragma unroll
      for (int k = 0; k < 2; ++k) {
        int dv = dv0 + 8*k;
        osum[u][qq][dv] = ored[u][0][dv][qq] + ored[u][1][dv][qq]
                        + ored[u][2][dv][qq] + ored[u][3][dv][qq];
      }
  }
  __syncthreads();
  {
    int qs = t >> 3, c2 = (t & 7)*2;
    #pragma unroll
    for (int u = 0; u < 2; ++u) {
      int q = q0 + u*32 + qs;
      if (q < LQ) {
        float invS = 1.f / sfin[u][qs];
        unsigned int lo = f2bf(osum[u][qs][c2]   * invS);
        unsigned int hi = f2bf(osum[u][qs][c2+1] * invS);
        *(unsigned int*)&Obf[((size_t)(b*LQ + q))*DD + h*DKK + c2] = lo | (hi << 16);
      }
    }
  }
}

// ---------------- fused proj + FF: X = out1 + ff(out1), out1 = X + Obf@Wo + bo ----------------
__global__ __launch_bounds__(256) void k_pff(const unsigned short* __restrict__ Obf,
        const unsigned short* __restrict__ Wot, const float* __restrict__ bo,
        const unsigned short* __restrict__ W1t, const float* __restrict__ b1,
        const unsigned short* __restrict__ W2t, const float* __restrict__ b2,
        float* __restrict__ X, unsigned short* __restrict__ Xbf) {
  __shared__ __align__(16) unsigned short LDSU[64 * HSTR];   // 66048 B, union T/Hs
  unsigned short* T  = LDSU;
  unsigned short* Hs = LDSU;
  int row0 = blockIdx.x * 64;
  int t = threadIdx.x, wave = t >> 6, lane = t & 63;
  int col = lane & 31, half = lane >> 5;
  int n = wave*32 + col;
  float res[2][16];
  {
    short8 a[2][8];
    const unsigned short* ob = Obf + (size_t)(row0 + col)*DD + half*8;
    #pragma unroll
    for (int mi = 0; mi < 2; ++mi)
      #pragma unroll
      for (int s = 0; s < 8; ++s)
        a[mi][s] = *(const short8*)(ob + (size_t)mi*32*DD + s*16);
    short8 bfr[8];
    const unsigned short* wb = Wot + (size_t)n*DD + half*8;
    #pragma unroll
    for (int s = 0; s < 8; ++s) bfr[s] = *(const short8*)(wb + s*16);
    f32x16 acc0 = {0.f,0.f,0.f,0.f,0.f,0.f,0.f,0.f,0.f,0.f,0.f,0.f,0.f,0.f,0.f,0.f};
    f32x16 acc1 = acc0;
    #pragma unroll
    for (int s = 0; s < 8; ++s) {
      acc0 = __builtin_amdgcn_mfma_f32_32x32x16_bf16(a[0][s], bfr[s], acc0, 0, 0, 0);
      acc1 = __builtin_amdgcn_mfma_f32_32x32x16_bf16(a[1][s], bfr[s], acc1, 0, 0, 0);
    }
    float bv = bo[n];
    #pragma unroll
    for (int mi = 0; mi < 2; ++mi) {
      const f32x16& acc = mi ? acc1 : acc0;
      #pragma unroll
      for (int r = 0; r < 16; ++r) {
        int ml = mi*32 + (r&3) + 8*(r>>2) + 4*half;
        size_t off = (size_t)(row0 + ml)*DD + n;
        res[mi][r] = X[off] + acc[r] + bv;
        T[ml*TSTR + n] = f2bf(res[mi][r]);
      }
    }
  }
  __syncthreads();
  short8 aF[2][8];
  #pragma unroll
  for (int mi = 0; mi < 2; ++mi)
    #pragma unroll
    for (int s = 0; s < 8; ++s) {
      const unsigned short* tp = &T[(mi*32 + col)*TSTR + half*8 + s*16];
      union { short4v h[2]; short8 v; } u;
      u.h[0] = *(const short4v*)tp;
      u.h[1] = *(const short4v*)(tp + 4);
      aF[mi][s] = u.v;
    }
  __syncthreads();
  #pragma unroll
  for (int nn = 0; nn < 4; ++nn) {
    int ni = wave*4 + nn;
    short8 bfr[8];
    const unsigned short* wb = W1t + (size_t)(ni*32 + col)*DD + half*8;
    #pragma unroll
    for (int s = 0; s < 8; ++s) bfr[s] = *(const short8*)(wb + s*16);
    f32x16 acc0 = {0.f,0.f,0.f,0.f,0.f,0.f,0.f,0.f,0.f,0.f,0.f,0.f,0.f,0.f,0.f,0.f};
    f32x16 acc1 = acc0;
    #pragma unroll
    for (int s = 0; s < 8; ++s) {
      acc0 = __builtin_amdgcn_mfma_f32_32x32x16_bf16(aF[0][s], bfr[s], acc0, 0, 0, 0);
      acc1 = __builtin_amdgcn_mfma_f32_32x32x16_bf16(aF[1][s], bfr[s], acc1, 0, 0, 0);
    }
    int nf = ni*32 + col;
    float bv = b1[nf];
    #pragma unroll
    for (int mi = 0; mi < 2; ++mi) {
      const f32x16& acc = mi ? acc1 : acc0;
      #pragma unroll
      for (int r = 0; r < 16; ++r) {
        int ml = mi*32 + (r&3) + 8*(r>>2) + 4*half;
        Hs[ml*HSTR + nf] = f2bf(fmaxf(acc[r] + bv, 0.f));
      }
    }
  }
  __syncthreads();
  f32x16 acc0 = {0.f,0.f,0.f,0.f,0.f,0.f,0.f,0.f,0.f,0.f,0.f,0.f,0.f,0.f,0.f,0.f};
  f32x16 acc1 = acc0;
  const unsigned short* w2b = W2t + (size_t)n*FFD + half*8;
  #pragma unroll 4
  for (int s = 0; s < 32; ++s) {
    int ko = s*16 + half*8;
    union { short4v h[2]; short8 v; } h0, h1;
    const unsigned short* hp0 = &Hs[col*HSTR + ko];
    const unsigned short* hp1 = &Hs[(32 + col)*HSTR + ko];
    h0.h[0] = *(const short4v*)hp0;  h0.h[1] = *(const short4v*)(hp0 + 4);
    h1.h[0] = *(const short4v*)hp1;  h1.h[1] = *(const short4v*)(hp1 + 4);
    short8 bfr = *(const short8*)(w2b + s*16);
    acc0 = __builtin_amdgcn_mfma_f32_32x32x16_bf16(h0.v, bfr, acc0, 0, 0, 0);
    acc1 = __builtin_amdgcn_mfma_f32_32x32x16_bf16(h1.v, bfr, acc1, 0, 0, 0);
  }
  float bv = b2[n];
  #pragma unroll
  for (int mi = 0; mi < 2; ++mi) {
    const f32x16& acc = mi ? acc1 : acc0;
    #pragma unroll
    for (int r = 0; r < 16; ++r) {
      int ml = mi*32 + (r&3) + 8*(r>>2) + 4*half;
      size_t off = (size_t)(row0 + ml)*DD + n;
      float v = res[mi][r] + acc[r] + bv;
      X[off] = v;
      Xbf[off] = f2bf(v);
    }
  }
}

// ---------------- logits: one wave per row ----------------
__global__ __launch_bounds__(256) void k_logits(const float* __restrict__ X,
                        const float* __restrict__ Wfin, const float* __restrict__ bfin,
                        float* __restrict__ logits) {
  int t = threadIdx.x, wave = t >> 6, lane = t & 63;
  int row = blockIdx.x*4 + wave;            // 6416*4 = 25664 exact
  float2 xv = *(const float2*)&X[(size_t)row*DD + lane*2];
  float2 wv = *(const float2*)&Wfin[lane*2];
  float v = xv.x*wv.x + xv.y*wv.y;
  #pragma unroll
  for (int off = 32; off > 0; off >>= 1) v += __shfl_down(v, off);
  if (lane == 0) logits[row] = v + bfin[0];
}

// ---------------- bias add, softmax, epsilon, scatter ----------------
__global__ __launch_bounds__(256) void k_final(const float* __restrict__ logits,
                       const float* __restrict__ AB, const int* __restrict__ sel,
                       const int* __restrict__ unselect, const int* __restrict__ pos,
                       float* __restrict__ out) {
  int b = blockIdx.x, t = threadIdx.x;
  __shared__ float sl[800];
  __shared__ float red[256];
  int lastsel = sel[b*SS + SS-1];
  const float* abrow = AB + ((size_t)b*NN + lastsel)*NN;
  for (int j = t; j < 800; j += 256)
    sl[j] = logits[b*LQ + j + 1] + abrow[unselect[b*800 + j]];
  __syncthreads();
  float lm = -INFINITY;
  for (int j = t; j < 800; j += 256) lm = fmaxf(lm, sl[j]);
  red[t] = lm;
  __syncthreads();
  for (int s = 128; s > 0; s >>= 1) {
    if (t < s) red[t] = fmaxf(red[t], red[t+s]);
    __syncthreads();
  }
  float m = red[0];
  __syncthreads();
  float ls = 0.f;
  for (int j = t; j < 800; j += 256) ls += __expf(sl[j] - m);
  red[t] = ls;
  __syncthreads();
  for (int s = 128; s > 0; s >>= 1) {
    if (t < s) red[t] += red[t+s];
    __syncthreads();
  }
  float inv = 1.f / red[0];
  for (int n = t; n < NN; n += 256) {
    int p1 = pos[b*NN + n];
    float v = -2.0f;
    if (p1 >= 0) {
      float p = __expf(sl[p1-1] - m) * inv;
      if (p <= 1e-5f) p += 1e-7f;
      v = p;
    }
    out[(size_t)b*NN + n] = v;
  }
}

extern "C" void kernel_launch(void* const* d_in, const int* in_sizes, int n_in,
                              void* d_out, int out_size, void* d_ws, size_t ws_size,
                              hipStream_t stream) {
  const float* data   = (const float*)d_in[0];
  const float* AB     = (const float*)d_in[1];
  const float* Wfirst = (const float*)d_in[2];
  const float* bfirst = (const float*)d_in[3];
  const float* Wlast  = (const float*)d_in[4];
  const float* blast  = (const float*)d_in[5];
  const float* Wq     = (const float*)d_in[6];
  const float* Wk     = (const float*)d_in[7];
  const float* Wv     = (const float*)d_in[8];
  const float* Wo     = (const float*)d_in[9];
  const float* bo     = (const float*)d_in[10];
  const float* W1     = (const float*)d_in[11];
  const float* b1     = (const float*)d_in[12];
  const float* W2     = (const float*)d_in[13];
  const float* b2     = (const float*)d_in[14];
  const float* Wfin   = (const float*)d_in[15];
  const float* bfin   = (const float*)d_in[16];
  const int*   sel    = (const int*)d_in[17];
  float* out = (float*)d_out;
  (void)in_sizes; (void)n_in; (void)out_size; (void)ws_size;

  char* ws = (char*)d_ws;
  const size_t NELT = (size_t)MROWS * DD;        // 3,284,992
  const size_t KVELT = (size_t)NB*HH*LPAD*DKK;   // 3,407,872
  int*   UNSEL = (int*)ws;
  int*   POS   = (int*)(ws + 102400);
  float* X     = (float*)(ws + 230400);
  unsigned short* Xbf = (unsigned short*)(X + NELT);
  unsigned short* Ob  = Xbf + NELT;
  unsigned short* Qb  = Ob + NELT;
  unsigned short* Kb  = Qb + KVELT;
  unsigned short* Vb  = Kb + KVELT;
  unsigned short* Vt  = Vb + KVELT;
  unsigned short* WtQKV = Vt + KVELT;
  unsigned short* Wot = WtQKV + (size_t)NLAYER*384*128;
  unsigned short* W1t = Wot + (size_t)NLAYER*128*128;
  unsigned short* W2t = W1t + (size_t)NLAYER*512*128;
  float* LOG = (float*)(W2t + (size_t)NLAYER*128*512);

  k_wconv<<<(3*WCH + 255)/256, 256, 0, stream>>>(Wq, Wk, Wv, Wo, W1, W2, WtQKV, Wot, W1t, W2t);
  k_unselect<<<NB, 1024, 0, stream>>>(sel, UNSEL, POS);
  k_embed_ends<<<dim3(2, NB), 128, 0, stream>>>(data, sel, Wfirst, bfirst, Wlast, blast, X, Xbf);
  k_embed_mid<<<3200, 256, 0, stream>>>(data, UNSEL, X, Xbf);
  for (int i = 0; i < NLAYER; ++i) {
    k_qkv_mfma<<<NBLK64, 256, 0, stream>>>(Xbf, WtQKV + (size_t)i*384*128, Qb, Kb, Vb);
    k_vt<<<dim3(13, NB*HH), 256, 0, stream>>>(Vb, Vt, Kb);
    k_attn3<<<NQT64*HH*NB, 256, 0, stream>>>(Qb, Kb, Vt, Ob);
    k_pff<<<NBLK64, 256, 0, stream>>>(Ob, Wot + (size_t)i*128*128, bo + (size_t)i*DD,
                                      W1t + (size_t)i*512*128, b1 + (size_t)i*FFD,
                                      W2t + (size_t)i*128*512, b2 + (size_t)i*DD, X, Xbf);
  }
  k_logits<<<MROWS/4, 256, 0, stream>>>(X, Wfin, bfin, LOG);
  k_final<<<NB, 256, 0, stream>>>(LOG, AB, sel, UNSEL, POS, out);
}